// Round 25
// baseline (398.768 us; speedup 1.0000x reference)
//
#include <hip/hip_runtime.h>
#include <hip/hip_bf16.h>

#define NPIX   2500
#define EDIM   256
#define NHEADS 8
#define HDIM   32
#define NLVLS  3
#define NPTS   4
#define NZ     4
#define NCAMS  6
#define NQTOT  10000   // NPIX*NZ
#define NVAL   8400    // 6400+1600+400 value positions per cam
#define FFND   512
#define NCHUNK 10
#define KVCH   250     // NPIX / NCHUNK
#define VTROW  2504    // VbfT row stride (ushorts): 5008B, 16B-aligned

typedef __attribute__((ext_vector_type(8))) short short8;
typedef __attribute__((ext_vector_type(4))) float float4v;

__device__ __forceinline__ void level_params(int l, int& H, int& W, int& st) {
    if (l == 0)      { H = 64; W = 100; st = 0;    }
    else if (l == 1) { H = 32; W = 50;  st = 6400; }
    else             { H = 16; W = 25;  st = 8000; }
}

__device__ __forceinline__ unsigned short f2bf(float x) {
    unsigned int u = __builtin_bit_cast(unsigned int, x);
    return (unsigned short)((u + 0x7fffu + ((u >> 16) & 1u)) >> 16);
}

// project BEV anchor (pix, iz) into cam; returns valid, u, v (normalized)
__device__ __forceinline__ bool cam_project(const float* __restrict__ Mt,
                                            int pix, int iz, float& u, float& v)
{
    const int prow = pix / 50, pcol = pix % 50;
    const float x3 = (pcol + 0.5f) * 4.0f - 60.f;
    const float y3 = (prow + 0.5f) * 2.4f - 60.f;
    const float z3 = (iz + 0.5f) * 2.0f - 4.f;
    const float p0 = Mt[0] * x3 + Mt[1] * y3 + Mt[2]  * z3 + Mt[3];
    const float p1 = Mt[4] * x3 + Mt[5] * y3 + Mt[6]  * z3 + Mt[7];
    const float p2 = Mt[8] * x3 + Mt[9] * y3 + Mt[10] * z3 + Mt[11];
    const float dd = p2 + 1e-5f;
    u = p0 / dd * (1.f / 800.f);
    v = p1 / dd * (1.f / 512.f);
    return (p2 > 1e-5f) && (u > 0.f) && (u < 1.f) && (v > 0.f) && (v < 1.f);
}

// ------ merged feat transpose (all 3 levels, one launch): F[e][p] f32 -> featT bf16 --
__global__ __launch_bounds__(256) void transpose_feat_all_k(const float* __restrict__ feat0,
                                                            const float* __restrict__ feat1,
                                                            const float* __restrict__ feat2,
                                                            int t,
                                                            unsigned short* __restrict__ featT)
{
    const int cam = blockIdx.z;
    const int bx = blockIdx.x;
    const float* feat; int HW, lvl_off, p0;
    if (bx < 200)      { feat = feat0; HW = 6400; lvl_off = 0;    p0 = bx * 32;         }
    else if (bx < 250) { feat = feat1; HW = 1600; lvl_off = 6400; p0 = (bx - 200) * 32; }
    else               { feat = feat2; HW = 400;  lvl_off = 8000; p0 = (bx - 250) * 32; }
    const float* F = feat + (size_t)(t * NCAMS + cam) * EDIM * HW;
    unsigned short* T = featT + (size_t)cam * NVAL * EDIM;
    __shared__ float tile[32][33];
    const int e0 = blockIdx.y * 32;
    const int tp = threadIdx.x & 31, tr = threadIdx.x >> 5;
#pragma unroll
    for (int i = 0; i < 4; i++) {
        int e = e0 + tr + i * 8;
        int p = p0 + tp;
        tile[tr + i * 8][tp] = (p < HW) ? F[(size_t)e * HW + p] : 0.f;
    }
    __syncthreads();
#pragma unroll
    for (int i = 0; i < 4; i++) {
        int p = p0 + tr + i * 8;
        int e = e0 + tp;
        if (p < HW) T[(size_t)(lvl_off + p) * EDIM + e] = f2bf(tile[tp][tr + i * 8]);
    }
}

// ---------------- MFMA GEMM 64x64 (f32 A; f32 out) ----------------------------------
template<int ACT, int ADD>
__global__ __launch_bounds__(256) void gemm64_k(const float* __restrict__ A,
                                                const float* __restrict__ A2,
                                                const float* __restrict__ W,
                                                const float* __restrict__ bias,
                                                float* __restrict__ C,
                                                int M, int N, int K,
                                                size_t a_bs, size_t w_bs,
                                                size_t b_bs, size_t c_bs)
{
    __shared__ unsigned short As[64][44];
    __shared__ unsigned short Ws[64][44];
    const int m0 = blockIdx.y * 64;
    const int n0 = blockIdx.x * 64;
    const int tid = threadIdx.x;
    const float* Af = A + blockIdx.z * a_bs;
    const float* Wf = W + blockIdx.z * w_bs;
    const float* Bf = bias ? bias + blockIdx.z * b_bs : nullptr;
    float* Cb = C + blockIdx.z * c_bs;
    const int wave = tid >> 6, lane = tid & 63;
    const int wr = wave >> 1, wc = wave & 1;
    const int fr = lane & 15, fk = lane >> 4;
    float4v acc[2][2];
#pragma unroll
    for (int mi = 0; mi < 2; mi++)
#pragma unroll
        for (int ni = 0; ni < 2; ni++) { acc[mi][ni][0] = 0.f; acc[mi][ni][1] = 0.f;
                                         acc[mi][ni][2] = 0.f; acc[mi][ni][3] = 0.f; }
    const int srow = tid >> 2, sk = (tid & 3) * 8;
    for (int k0 = 0; k0 < K; k0 += 32) {
        unsigned short tmp[8];
        {
            const int gr = m0 + srow;
            if (gr < M) {
                const float* src = Af + (size_t)gr * K + k0 + sk;
                if (ADD) {
                    const float* src2 = A2 + (size_t)gr * K + k0 + sk;
#pragma unroll
                    for (int j = 0; j < 8; j++) tmp[j] = f2bf(src[j] + src2[j]);
                } else {
#pragma unroll
                    for (int j = 0; j < 8; j++) tmp[j] = f2bf(src[j]);
                }
            } else {
#pragma unroll
                for (int j = 0; j < 8; j++) tmp[j] = 0;
            }
            *(short8*)&As[srow][sk] = *(short8*)&tmp[0];
        }
        {
            const int gw = n0 + srow;
            if (gw < N) {
                const float* src = Wf + (size_t)gw * K + k0 + sk;
#pragma unroll
                for (int j = 0; j < 8; j++) tmp[j] = f2bf(src[j]);
            } else {
#pragma unroll
                for (int j = 0; j < 8; j++) tmp[j] = 0;
            }
            *(short8*)&Ws[srow][sk] = *(short8*)&tmp[0];
        }
        __syncthreads();
        short8 af[2], bfr[2];
#pragma unroll
        for (int mi = 0; mi < 2; mi++)
            af[mi] = *(const short8*)&As[wr * 32 + mi * 16 + fr][fk * 8];
#pragma unroll
        for (int ni = 0; ni < 2; ni++)
            bfr[ni] = *(const short8*)&Ws[wc * 32 + ni * 16 + fr][fk * 8];
#pragma unroll
        for (int mi = 0; mi < 2; mi++)
#pragma unroll
            for (int ni = 0; ni < 2; ni++)
                acc[mi][ni] = __builtin_amdgcn_mfma_f32_16x16x32_bf16(
                    af[mi], bfr[ni], acc[mi][ni], 0, 0, 0);
        __syncthreads();
    }
#pragma unroll
    for (int mi = 0; mi < 2; mi++)
#pragma unroll
        for (int ni = 0; ni < 2; ni++) {
            const int col = n0 + wc * 32 + ni * 16 + fr;
#pragma unroll
            for (int r = 0; r < 4; r++) {
                const int row = m0 + wr * 32 + mi * 16 + fk * 4 + r;
                if (row < M && col < N) {
                    float v = acc[mi][ni][r] + (Bf ? Bf[col] : 0.f);
                    if (ACT) v = fmaxf(v, 0.f);
                    Cb[(size_t)row * N + col] = v;
                }
            }
        }
}

// ---------------- MFMA GEMM 64x64, f32 A -> bf16 OUT (generic M/N/K) -----------------
template<int ACT, int ADD>
__global__ __launch_bounds__(256) void gemm64o_k(const float* __restrict__ A,
                                                 const float* __restrict__ A2,
                                                 const float* __restrict__ W,
                                                 const float* __restrict__ bias,
                                                 unsigned short* __restrict__ C,
                                                 int M, int N, int K)
{
    __shared__ unsigned short As[64][44];
    __shared__ unsigned short Ws[64][44];
    const int m0 = blockIdx.y * 64;
    const int n0 = blockIdx.x * 64;
    const int tid = threadIdx.x;
    const int wave = tid >> 6, lane = tid & 63;
    const int wr = wave >> 1, wc = wave & 1;
    const int fr = lane & 15, fk = lane >> 4;
    float4v acc[2][2];
#pragma unroll
    for (int mi = 0; mi < 2; mi++)
#pragma unroll
        for (int ni = 0; ni < 2; ni++) { acc[mi][ni][0] = 0.f; acc[mi][ni][1] = 0.f;
                                         acc[mi][ni][2] = 0.f; acc[mi][ni][3] = 0.f; }
    const int srow = tid >> 2, sk = (tid & 3) * 8;
    for (int k0 = 0; k0 < K; k0 += 32) {
        unsigned short tmp[8];
        {
            const int gr = m0 + srow;
            if (gr < M) {
                const float* src = A + (size_t)gr * K + k0 + sk;
                if (ADD) {
                    const float* src2 = A2 + (size_t)gr * K + k0 + sk;
#pragma unroll
                    for (int j = 0; j < 8; j++) tmp[j] = f2bf(src[j] + src2[j]);
                } else {
#pragma unroll
                    for (int j = 0; j < 8; j++) tmp[j] = f2bf(src[j]);
                }
            } else {
#pragma unroll
                for (int j = 0; j < 8; j++) tmp[j] = 0;
            }
            *(short8*)&As[srow][sk] = *(short8*)&tmp[0];
        }
        {
            const int gw = n0 + srow;
            if (gw < N) {
                const float* src = W + (size_t)gw * K + k0 + sk;
#pragma unroll
                for (int j = 0; j < 8; j++) tmp[j] = f2bf(src[j]);
            } else {
#pragma unroll
                for (int j = 0; j < 8; j++) tmp[j] = 0;
            }
            *(short8*)&Ws[srow][sk] = *(short8*)&tmp[0];
        }
        __syncthreads();
        short8 af[2], bfr[2];
#pragma unroll
        for (int mi = 0; mi < 2; mi++)
            af[mi] = *(const short8*)&As[wr * 32 + mi * 16 + fr][fk * 8];
#pragma unroll
        for (int ni = 0; ni < 2; ni++)
            bfr[ni] = *(const short8*)&Ws[wc * 32 + ni * 16 + fr][fk * 8];
#pragma unroll
        for (int mi = 0; mi < 2; mi++)
#pragma unroll
            for (int ni = 0; ni < 2; ni++)
                acc[mi][ni] = __builtin_amdgcn_mfma_f32_16x16x32_bf16(
                    af[mi], bfr[ni], acc[mi][ni], 0, 0, 0);
        __syncthreads();
    }
#pragma unroll
    for (int mi = 0; mi < 2; mi++)
#pragma unroll
        for (int ni = 0; ni < 2; ni++) {
            const int col = n0 + wc * 32 + ni * 16 + fr;
#pragma unroll
            for (int r = 0; r < 4; r++) {
                const int row = m0 + wr * 32 + mi * 16 + fk * 4 + r;
                if (row < M && col < N) {
                    float v = acc[mi][ni][r] + (bias ? bias[col] : 0.f);
                    if (ACT) v = fmaxf(v, 0.f);
                    C[(size_t)row * N + col] = f2bf(v);
                }
            }
        }
}

// ---------- merged QKV GEMM: z=0 -> Qbf (scaled), z=1 -> Kbf, z=2 -> VbfT (trans) ----
__global__ __launch_bounds__(256) void gemm_qkv_k(const float* __restrict__ bev_emb,
                                                  const float* __restrict__ prev_al,
                                                  const float* __restrict__ bev_pose,
                                                  const float* __restrict__ ta_in_w,
                                                  const float* __restrict__ ta_in_b,
                                                  unsigned short* __restrict__ Qbf,
                                                  unsigned short* __restrict__ Kbf,
                                                  unsigned short* __restrict__ VbfT)
{
    __shared__ unsigned short As[64][44];
    __shared__ unsigned short Ws[64][44];
    const int z = blockIdx.z;
    const float* A    = (z == 0) ? bev_emb : prev_al;
    const float* A2   = (z == 2) ? nullptr : bev_pose;
    const float* W    = ta_in_w + (size_t)z * EDIM * EDIM;
    const float* bias = ta_in_b + z * EDIM;
    const float oscale = (z == 0) ? 0.17677669529663689f : 1.0f;
    unsigned short* C = (z == 0) ? Qbf : (z == 1) ? Kbf : VbfT;
    const int m0 = blockIdx.y * 64;
    const int n0 = blockIdx.x * 64;
    const int tid = threadIdx.x;
    const int wave = tid >> 6, lane = tid & 63;
    const int wr = wave >> 1, wc = wave & 1;
    const int fr = lane & 15, fk = lane >> 4;
    float4v acc[2][2];
#pragma unroll
    for (int mi = 0; mi < 2; mi++)
#pragma unroll
        for (int ni = 0; ni < 2; ni++) { acc[mi][ni][0] = 0.f; acc[mi][ni][1] = 0.f;
                                         acc[mi][ni][2] = 0.f; acc[mi][ni][3] = 0.f; }
    const int srow = tid >> 2, sk = (tid & 3) * 8;
    for (int k0 = 0; k0 < EDIM; k0 += 32) {
        unsigned short tmp[8];
        {
            const int gr = m0 + srow;
            if (gr < NPIX) {
                const float* src = A + (size_t)gr * EDIM + k0 + sk;
                if (A2) {
                    const float* src2 = A2 + (size_t)gr * EDIM + k0 + sk;
#pragma unroll
                    for (int j = 0; j < 8; j++) tmp[j] = f2bf(src[j] + src2[j]);
                } else {
#pragma unroll
                    for (int j = 0; j < 8; j++) tmp[j] = f2bf(src[j]);
                }
            } else {
#pragma unroll
                for (int j = 0; j < 8; j++) tmp[j] = 0;
            }
            *(short8*)&As[srow][sk] = *(short8*)&tmp[0];
        }
        {
            const float* src = W + (size_t)(n0 + srow) * EDIM + k0 + sk;
#pragma unroll
            for (int j = 0; j < 8; j++) tmp[j] = f2bf(src[j]);
            *(short8*)&Ws[srow][sk] = *(short8*)&tmp[0];
        }
        __syncthreads();
        short8 af[2], bfr[2];
#pragma unroll
        for (int mi = 0; mi < 2; mi++)
            af[mi] = *(const short8*)&As[wr * 32 + mi * 16 + fr][fk * 8];
#pragma unroll
        for (int ni = 0; ni < 2; ni++)
            bfr[ni] = *(const short8*)&Ws[wc * 32 + ni * 16 + fr][fk * 8];
#pragma unroll
        for (int mi = 0; mi < 2; mi++)
#pragma unroll
            for (int ni = 0; ni < 2; ni++)
                acc[mi][ni] = __builtin_amdgcn_mfma_f32_16x16x32_bf16(
                    af[mi], bfr[ni], acc[mi][ni], 0, 0, 0);
        __syncthreads();
    }
#pragma unroll
    for (int mi = 0; mi < 2; mi++)
#pragma unroll
        for (int ni = 0; ni < 2; ni++) {
            const int col = n0 + wc * 32 + ni * 16 + fr;
#pragma unroll
            for (int r = 0; r < 4; r++) {
                const int row = m0 + wr * 32 + mi * 16 + fk * 4 + r;
                if (row < NPIX) {
                    const float v = (acc[mi][ni][r] + bias[col]) * oscale;
                    if (z == 2)
                        C[(size_t)col * VTROW + row] = f2bf(v);
                    else
                        C[(size_t)row * EDIM + col] = f2bf(v);
                }
            }
        }
}

// ---------------- MFMA GEMM 64x64, bf16 A; nullable bias ----------------------------
__global__ __launch_bounds__(256) void gemm64b_k(const unsigned short* __restrict__ A,
                                                 const float* __restrict__ W,
                                                 const float* __restrict__ bias,
                                                 float* __restrict__ C,
                                                 int M, int N, int K,
                                                 size_t a_bs, size_t c_bs)
{
    __shared__ unsigned short As[64][44];
    __shared__ unsigned short Ws[64][44];
    const int m0 = blockIdx.y * 64;
    const int n0 = blockIdx.x * 64;
    const int tid = threadIdx.x;
    const unsigned short* Af = A + blockIdx.z * a_bs;
    float* Cb = C + blockIdx.z * c_bs;
    const int wave = tid >> 6, lane = tid & 63;
    const int wr = wave >> 1, wc = wave & 1;
    const int fr = lane & 15, fk = lane >> 4;
    float4v acc[2][2];
#pragma unroll
    for (int mi = 0; mi < 2; mi++)
#pragma unroll
        for (int ni = 0; ni < 2; ni++) { acc[mi][ni][0] = 0.f; acc[mi][ni][1] = 0.f;
                                         acc[mi][ni][2] = 0.f; acc[mi][ni][3] = 0.f; }
    const int srow = tid >> 2, sk = (tid & 3) * 8;
    for (int k0 = 0; k0 < K; k0 += 32) {
        {
            const int gr = m0 + srow;
            if (gr < M) {
                *(short8*)&As[srow][sk] =
                    *(const short8*)&Af[(size_t)gr * K + k0 + sk];
            } else {
                short8 z = {0,0,0,0,0,0,0,0};
                *(short8*)&As[srow][sk] = z;
            }
        }
        {
            unsigned short tmp[8];
            const int gw = n0 + srow;
            if (gw < N) {
                const float* src = W + (size_t)gw * K + k0 + sk;
#pragma unroll
                for (int j = 0; j < 8; j++) tmp[j] = f2bf(src[j]);
            } else {
#pragma unroll
                for (int j = 0; j < 8; j++) tmp[j] = 0;
            }
            *(short8*)&Ws[srow][sk] = *(short8*)&tmp[0];
        }
        __syncthreads();
        short8 af[2], bfr[2];
#pragma unroll
        for (int mi = 0; mi < 2; mi++)
            af[mi] = *(const short8*)&As[wr * 32 + mi * 16 + fr][fk * 8];
#pragma unroll
        for (int ni = 0; ni < 2; ni++)
            bfr[ni] = *(const short8*)&Ws[wc * 32 + ni * 16 + fr][fk * 8];
#pragma unroll
        for (int mi = 0; mi < 2; mi++)
#pragma unroll
            for (int ni = 0; ni < 2; ni++)
                acc[mi][ni] = __builtin_amdgcn_mfma_f32_16x16x32_bf16(
                    af[mi], bfr[ni], acc[mi][ni], 0, 0, 0);
        __syncthreads();
    }
#pragma unroll
    for (int mi = 0; mi < 2; mi++)
#pragma unroll
        for (int ni = 0; ni < 2; ni++) {
            const int col = n0 + wc * 32 + ni * 16 + fr;
#pragma unroll
            for (int r = 0; r < 4; r++) {
                const int row = m0 + wr * 32 + mi * 16 + fk * 4 + r;
                if (row < M && col < N)
                    Cb[(size_t)row * N + col] = acc[mi][ni][r] + (bias ? bias[col] : 0.f);
            }
        }
}

// ------ merged vproj (z=0..5, bf16 A) + so/aw (z=6, f32 A+A2) GEMM, one launch -------
__global__ __launch_bounds__(256) void gemm_vs_k(const unsigned short* __restrict__ featT,
                                                 const float* __restrict__ vp_w,
                                                 const float* __restrict__ vp_b,
                                                 float* __restrict__ vproj,
                                                 const float* __restrict__ Aso,
                                                 const float* __restrict__ A2so,
                                                 const float* __restrict__ Wso,
                                                 const float* __restrict__ Waw,
                                                 const float* __restrict__ Bso,
                                                 const float* __restrict__ Baw,
                                                 float* __restrict__ Cso)
{
    const int z = blockIdx.z;
    const bool so = (z == 6);
    if (!so && blockIdx.x >= 4) return;   // vproj: N=256 -> 4 col tiles
    if (so && blockIdx.y >= 40) return;   // soaw: M=2500 -> 40 row tiles
    __shared__ unsigned short As[64][44];
    __shared__ unsigned short Ws[64][44];
    const int m0 = blockIdx.y * 64;
    const int n0 = blockIdx.x * 64;
    const int tid = threadIdx.x;
    const int wave = tid >> 6, lane = tid & 63;
    const int wr = wave >> 1, wc = wave & 1;
    const int fr = lane & 15, fk = lane >> 4;
    const unsigned short* Af = featT + (size_t)z * NVAL * EDIM;  // z<6 only
    const int M = so ? NPIX : NVAL;
    float4v acc[2][2];
#pragma unroll
    for (int mi = 0; mi < 2; mi++)
#pragma unroll
        for (int ni = 0; ni < 2; ni++) { acc[mi][ni][0] = 0.f; acc[mi][ni][1] = 0.f;
                                         acc[mi][ni][2] = 0.f; acc[mi][ni][3] = 0.f; }
    const int srow = tid >> 2, sk = (tid & 3) * 8;
    for (int k0 = 0; k0 < EDIM; k0 += 32) {
        unsigned short tmp[8];
        {
            const int gr = m0 + srow;
            if (so) {
                if (gr < NPIX) {
                    const float* src  = Aso  + (size_t)gr * EDIM + k0 + sk;
                    const float* src2 = A2so + (size_t)gr * EDIM + k0 + sk;
#pragma unroll
                    for (int j = 0; j < 8; j++) tmp[j] = f2bf(src[j] + src2[j]);
                } else {
#pragma unroll
                    for (int j = 0; j < 8; j++) tmp[j] = 0;
                }
                *(short8*)&As[srow][sk] = *(short8*)&tmp[0];
            } else {
                if (gr < NVAL) {
                    *(short8*)&As[srow][sk] =
                        *(const short8*)&Af[(size_t)gr * EDIM + k0 + sk];
                } else {
                    short8 zr = {0,0,0,0,0,0,0,0};
                    *(short8*)&As[srow][sk] = zr;
                }
            }
        }
        {
            const int gw = n0 + srow;
            const float* src;
            if (so)
                src = (gw < 192) ? Wso + (size_t)gw * EDIM + k0 + sk
                    : (gw < 288) ? Waw + (size_t)(gw - 192) * EDIM + k0 + sk
                                 : nullptr;
            else
                src = vp_w + (size_t)gw * EDIM + k0 + sk;
            if (src) {
#pragma unroll
                for (int j = 0; j < 8; j++) tmp[j] = f2bf(src[j]);
            } else {
#pragma unroll
                for (int j = 0; j < 8; j++) tmp[j] = 0;
            }
            *(short8*)&Ws[srow][sk] = *(short8*)&tmp[0];
        }
        __syncthreads();
        short8 af[2], bfr[2];
#pragma unroll
        for (int mi = 0; mi < 2; mi++)
            af[mi] = *(const short8*)&As[wr * 32 + mi * 16 + fr][fk * 8];
#pragma unroll
        for (int ni = 0; ni < 2; ni++)
            bfr[ni] = *(const short8*)&Ws[wc * 32 + ni * 16 + fr][fk * 8];
#pragma unroll
        for (int mi = 0; mi < 2; mi++)
#pragma unroll
            for (int ni = 0; ni < 2; ni++)
                acc[mi][ni] = __builtin_amdgcn_mfma_f32_16x16x32_bf16(
                    af[mi], bfr[ni], acc[mi][ni], 0, 0, 0);
        __syncthreads();
    }
#pragma unroll
    for (int mi = 0; mi < 2; mi++)
#pragma unroll
        for (int ni = 0; ni < 2; ni++) {
            const int col = n0 + wc * 32 + ni * 16 + fr;
#pragma unroll
            for (int r = 0; r < 4; r++) {
                const int row = m0 + wr * 32 + mi * 16 + fk * 4 + r;
                if (row < M) {
                    if (so) {
                        if (col < 288) {
                            const float b = (col < 192) ? Bso[col] : Baw[col - 192];
                            Cso[(size_t)row * 288 + col] = acc[mi][ni][r] + b;
                        }
                    } else {
                        vproj[((size_t)z * NVAL + row) * EDIM + col] =
                            acc[mi][ni][r] + vp_b[col];
                    }
                }
            }
        }
}

// ------ op-proj GEMM with fused Z-reduce A-staging; sfac recomputed inline ----------
__global__ __launch_bounds__(256) void gemm_op_k(const float* __restrict__ S,
                                                 const float* __restrict__ l2i, int t,
                                                 const float* __restrict__ W,
                                                 float* __restrict__ C)
{
    __shared__ unsigned short As[64][44];
    __shared__ unsigned short Ws[64][44];
    __shared__ float sfac[256];
    const int m0 = blockIdx.y * 64;
    const int n0 = blockIdx.x * 64;
    const int tid = threadIdx.x;
    {
        const int idx = m0 * 4 + tid;
        float sf = 1.f;
        if (idx < NQTOT) {
            const int pix = idx >> 2, iz = idx & 3;
            int vcount = 0;
#pragma unroll
            for (int cam = 0; cam < NCAMS; cam++) {
                float u, v;
                if (cam_project(l2i + (size_t)(t * NCAMS + cam) * 16, pix, iz, u, v))
                    vcount++;
            }
            sf = 1.f / fmaxf((float)vcount, 1.f);
        }
        sfac[tid] = sf;
    }
    __syncthreads();
    const int wave = tid >> 6, lane = tid & 63;
    const int wr = wave >> 1, wc = wave & 1;
    const int fr = lane & 15, fk = lane >> 4;
    float4v acc[2][2];
#pragma unroll
    for (int mi = 0; mi < 2; mi++)
#pragma unroll
        for (int ni = 0; ni < 2; ni++) { acc[mi][ni][0] = 0.f; acc[mi][ni][1] = 0.f;
                                         acc[mi][ni][2] = 0.f; acc[mi][ni][3] = 0.f; }
    const int srow = tid >> 2, sk = (tid & 3) * 8;
    for (int k0 = 0; k0 < EDIM; k0 += 32) {
        unsigned short tmp[8];
        {
            const int gr = m0 + srow;
            if (gr < NPIX) {
                float sum[8];
#pragma unroll
                for (int j = 0; j < 8; j++) sum[j] = 0.f;
#pragma unroll
                for (int iz = 0; iz < NZ; iz++) {
                    const float* src = S + ((size_t)(gr * 4 + iz) * EDIM + k0 + sk);
                    const float f = sfac[srow * 4 + iz];
#pragma unroll
                    for (int j = 0; j < 8; j++) sum[j] += src[j] * f;
                }
#pragma unroll
                for (int j = 0; j < 8; j++) tmp[j] = f2bf(sum[j] * 0.25f);
            } else {
#pragma unroll
                for (int j = 0; j < 8; j++) tmp[j] = 0;
            }
            *(short8*)&As[srow][sk] = *(short8*)&tmp[0];
        }
        {
            const float* src = W + (size_t)(n0 + srow) * EDIM + k0 + sk;
#pragma unroll
            for (int j = 0; j < 8; j++) tmp[j] = f2bf(src[j]);
            *(short8*)&Ws[srow][sk] = *(short8*)&tmp[0];
        }
        __syncthreads();
        short8 af[2], bfr[2];
#pragma unroll
        for (int mi = 0; mi < 2; mi++)
            af[mi] = *(const short8*)&As[wr * 32 + mi * 16 + fr][fk * 8];
#pragma unroll
        for (int ni = 0; ni < 2; ni++)
            bfr[ni] = *(const short8*)&Ws[wc * 32 + ni * 16 + fr][fk * 8];
#pragma unroll
        for (int mi = 0; mi < 2; mi++)
#pragma unroll
            for (int ni = 0; ni < 2; ni++)
                acc[mi][ni] = __builtin_amdgcn_mfma_f32_16x16x32_bf16(
                    af[mi], bfr[ni], acc[mi][ni], 0, 0, 0);
        __syncthreads();
    }
#pragma unroll
    for (int mi = 0; mi < 2; mi++)
#pragma unroll
        for (int ni = 0; ni < 2; ni++) {
            const int col = n0 + wc * 32 + ni * 16 + fr;
#pragma unroll
            for (int r = 0; r < 4; r++) {
                const int row = m0 + wr * 32 + mi * 16 + fk * 4 + r;
                if (row < NPIX)
                    C[(size_t)row * EDIM + col] = acc[mi][ni][r];
            }
        }
}

// ------- residual + LayerNorm (TRANS: transposed out; VBM: recompute vbm inline) -----
template<int TRANS, int VBM>
__global__ __launch_bounds__(256) void resid_ln_k(const float* __restrict__ x0,
                                                  const float* __restrict__ x1,
                                                  const float* __restrict__ cvec,
                                                  const float* __restrict__ l2i, int t,
                                                  const float* __restrict__ g,
                                                  const float* __restrict__ bta,
                                                  float* __restrict__ out)
{
    const int row = blockIdx.x, e = threadIdx.x;
    __shared__ float red[256];
    __shared__ float svbm;
    if (VBM) {
        if (e < 4) {
            int vcount = 0;
#pragma unroll
            for (int cam = 0; cam < NCAMS; cam++) {
                float u, v;
                if (cam_project(l2i + (size_t)(t * NCAMS + cam) * 16, row, e, u, v))
                    vcount++;
            }
            float ind = (vcount > 0) ? 1.f : 0.f;
            ind += __shfl_xor(ind, 1);
            ind += __shfl_xor(ind, 2);
            if (e == 0) svbm = ind * 0.25f;
        }
        __syncthreads();
    }
    float x = x0[(size_t)row * EDIM + e] + x1[(size_t)row * EDIM + e];
    if (VBM) x += cvec[e] * svbm;
    red[e] = x; __syncthreads();
    for (int s = 128; s > 0; s >>= 1) { if (e < s) red[e] += red[e + s]; __syncthreads(); }
    float mean = red[0] * (1.f / 256.f);
    __syncthreads();
    float dx = x - mean;
    red[e] = dx * dx; __syncthreads();
    for (int s = 128; s > 0; s >>= 1) { if (e < s) red[e] += red[e + s]; __syncthreads(); }
    float var = red[0] * (1.f / 256.f);
    const float res = dx * rsqrtf(var + 1e-5f) * g[e] + bta[e];
    if (TRANS)
        out[(size_t)e * NPIX + row] = res;
    else
        out[(size_t)row * EDIM + e] = res;
}

// ------- deformable sampling v5: uv + aw-softmax computed in-block; waves split pts --
__global__ __launch_bounds__(256) void spatial_sample_k(const float* __restrict__ vproj,
                                                        const float* __restrict__ offb,
                                                        const float* __restrict__ l2i,
                                                        int t,
                                                        float* __restrict__ S)
{
    const int n = blockIdx.x;
    const int tid = threadIdx.x;
    const int wave = tid >> 6, lane = tid & 63;
    const int ch0 = lane << 2;
    const int h = lane >> 3;
    const int pix = n >> 2;
    __shared__ float soff[192];
    __shared__ float saw[96];
    __shared__ float suv[12];
    __shared__ float red[3][256];
    if (tid < 192) soff[tid] = offb[(size_t)pix * 288 + tid];
    if (tid < 96)  saw[tid]  = offb[(size_t)pix * 288 + 192 + tid];
    if (tid < 6) {
        float u, v;
        const bool valid = cam_project(l2i + (size_t)(t * NCAMS + tid) * 16,
                                       pix, n & 3, u, v);
        suv[tid * 2]     = valid ? u : -1.f;
        suv[tid * 2 + 1] = v;
    }
    __syncthreads();
    if (tid < 8) {   // per-head 12-wide softmax on raw aw
        float m = -3.0e38f;
#pragma unroll
        for (int j = 0; j < 12; j++) m = fmaxf(m, saw[tid * 12 + j]);
        float ex[12]; float s = 0.f;
#pragma unroll
        for (int j = 0; j < 12; j++) { ex[j] = __expf(saw[tid * 12 + j] - m); s += ex[j]; }
        const float inv = 1.f / s;
#pragma unroll
        for (int j = 0; j < 12; j++) saw[tid * 12 + j] = ex[j] * inv;
    }
    __syncthreads();
    float4 acc = make_float4(0.f, 0.f, 0.f, 0.f);
    for (int cam = 0; cam < NCAMS; cam++) {
        const float u = suv[cam * 2];
        if (u < 0.f) continue;
        const float v = suv[cam * 2 + 1];
        const float* vc = vproj + (size_t)cam * NVAL * EDIM + ch0;
        for (int pt = wave; pt < NLVLS * NPTS; pt += 4) {
            const int l = pt >> 2, p = pt & 3;
            int Hl, Wl, st; level_params(l, Hl, Wl, st);
            const int ob = ((h * NLVLS + l) * NPTS + p) * 2;
            const float x = u * (float)Wl + soff[ob]     - 0.5f;
            const float y = v * (float)Hl + soff[ob + 1] - 0.5f;
            const float xf = floorf(x), yf = floorf(y);
            const float wx = x - xf, wy = y - yf;
            const int x0 = (int)xf, y0 = (int)yf;
            const float a = saw[(h * NLVLS + l) * NPTS + p];
            const bool xi0 = (x0 >= 0) & (x0 < Wl);
            const bool xi1 = (x0 + 1 >= 0) & (x0 + 1 < Wl);
            const bool yi0 = (y0 >= 0) & (y0 < Hl);
            const bool yi1 = (y0 + 1 >= 0) & (y0 + 1 < Hl);
            const int rb = st + y0 * Wl + x0;
            float4 sv = make_float4(0.f, 0.f, 0.f, 0.f);
            if (yi0 & xi0) {
                const float w00 = (1.f - wy) * (1.f - wx);
                const float4 t4 = *(const float4*)(vc + ((size_t)rb << 8));
                sv.x += w00 * t4.x; sv.y += w00 * t4.y; sv.z += w00 * t4.z; sv.w += w00 * t4.w;
            }
            if (yi0 & xi1) {
                const float w01 = (1.f - wy) * wx;
                const float4 t4 = *(const float4*)(vc + ((size_t)(rb + 1) << 8));
                sv.x += w01 * t4.x; sv.y += w01 * t4.y; sv.z += w01 * t4.z; sv.w += w01 * t4.w;
            }
            if (yi1 & xi0) {
                const float w10 = wy * (1.f - wx);
                const float4 t4 = *(const float4*)(vc + ((size_t)(rb + Wl) << 8));
                sv.x += w10 * t4.x; sv.y += w10 * t4.y; sv.z += w10 * t4.z; sv.w += w10 * t4.w;
            }
            if (yi1 & xi1) {
                const float w11 = wy * wx;
                const float4 t4 = *(const float4*)(vc + ((size_t)(rb + Wl + 1) << 8));
                sv.x += w11 * t4.x; sv.y += w11 * t4.y; sv.z += w11 * t4.z; sv.w += w11 * t4.w;
            }
            acc.x += a * sv.x; acc.y += a * sv.y; acc.z += a * sv.z; acc.w += a * sv.w;
        }
    }
    if (wave > 0) *(float4*)&red[wave - 1][ch0] = acc;
    __syncthreads();
    if (wave == 0) {
#pragma unroll
        for (int w2 = 0; w2 < 3; w2++) {
            const float4 r4 = *(const float4*)&red[w2][ch0];
            acc.x += r4.x; acc.y += r4.y; acc.z += r4.z; acc.w += r4.w;
        }
        *(float4*)(S + (size_t)n * EDIM + ch0) = acc;
    }
}

// ---------------- temporal align (4x4 inverse fused, computed per block) -------------
__global__ __launch_bounds__(256) void talign_k(const float* __restrict__ prev,
                                                const float* __restrict__ motion,
                                                float* __restrict__ out)
{
    __shared__ float sinv[16];
    if (threadIdx.x == 0) {
        float a[4][8];
        for (int i = 0; i < 4; i++)
            for (int j = 0; j < 4; j++) { a[i][j] = motion[i * 4 + j];
                                          a[i][4 + j] = (i == j) ? 1.f : 0.f; }
        for (int col = 0; col < 4; col++) {
            int piv = col;
            for (int r = col + 1; r < 4; r++)
                if (fabsf(a[r][col]) > fabsf(a[piv][col])) piv = r;
            if (piv != col)
                for (int j = 0; j < 8; j++) { float tp = a[col][j];
                                              a[col][j] = a[piv][j]; a[piv][j] = tp; }
            float idv = 1.f / a[col][col];
            for (int j = 0; j < 8; j++) a[col][j] *= idv;
            for (int r = 0; r < 4; r++) {
                if (r == col) continue;
                float f = a[r][col];
                for (int j = 0; j < 8; j++) a[r][j] -= f * a[col][j];
            }
        }
        for (int i = 0; i < 4; i++)
            for (int j = 0; j < 4; j++) sinv[i * 4 + j] = a[i][4 + j];
    }
    __syncthreads();
    const int pix = blockIdx.x, e = threadIdx.x;
    const int r = pix / 50, c = pix % 50;
    const float rx = (c + 0.5f) * 4.0f - 60.f;
    const float ry = (r + 0.5f) * 2.4f - 60.f;
    const float gx = sinv[0] * rx + sinv[1] * ry + sinv[3];
    const float gy = sinv[4] * rx + sinv[5] * ry + sinv[7];
    const float nx = (gx + 60.f) * 0.01f - 1.f;
    const float ny = (gy + 60.f) * (1.f / 60.f) - 1.f;
    const float x = (nx + 1.f) * 25.f - 0.5f;
    const float y = (ny + 1.f) * 25.f - 0.5f;
    const float xf = floorf(x), yf = floorf(y);
    const float wx = x - xf, wy = y - yf;
    const int x0 = (int)xf, y0 = (int)yf;
    bool xi0 = (x0 >= 0 && x0 < 50), xi1 = (x0 + 1 >= 0 && x0 + 1 < 50);
    bool yi0 = (y0 >= 0 && y0 < 50), yi1 = (y0 + 1 >= 0 && y0 + 1 < 50);
    float s = 0.f;
    if (yi0 && xi0) s += (1.f - wy) * (1.f - wx) * prev[(size_t)(y0 * 50 + x0) * EDIM + e];
    if (yi0 && xi1) s += (1.f - wy) * wx         * prev[(size_t)(y0 * 50 + x0 + 1) * EDIM + e];
    if (yi1 && xi0) s += wy * (1.f - wx)         * prev[(size_t)((y0 + 1) * 50 + x0) * EDIM + e];
    if (yi1 && xi1) s += wy * wx                 * prev[(size_t)((y0 + 1) * 50 + x0 + 1) * EDIM + e];
    out[(size_t)pix * EDIM + e] = s;
}

// ---------------- MHA flash, MFMA, split-KV (bf16 inputs; full-tile fast path) ------
__global__ __launch_bounds__(256) void mha_mfma_k(const unsigned short* __restrict__ Qbf,
                                                  const unsigned short* __restrict__ Kbf,
                                                  const unsigned short* __restrict__ VbfT,
                                                  float* __restrict__ pacc,
                                                  float* __restrict__ pml)
{
    const int h = blockIdx.y;
    const int q0 = blockIdx.x * 64;
    const int chunk = blockIdx.z;
    const int kv0 = chunk * KVCH;
    const int kv1 = min(NPIX, kv0 + KVCH);
    const int tid = threadIdx.x;
    const int wave = tid >> 6, lane = tid & 63;
    const int fr = lane & 15, fk = lane >> 4;

    __shared__ unsigned short Qs[64][44];
    __shared__ unsigned short Ks[64][44];
    __shared__ unsigned short Vt[32][76];
    __shared__ unsigned short Ps[4][16][76];

    const int srow = tid >> 2, scs = tid & 3;
    {
        const int gq = q0 + srow;
        if (gq < NPIX)
            *(short8*)&Qs[srow][scs * 8] =
                *(const short8*)&Qbf[(size_t)gq * EDIM + h * HDIM + scs * 8];
        else {
            short8 z = {0,0,0,0,0,0,0,0};
            *(short8*)&Qs[srow][scs * 8] = z;
        }
    }
    __syncthreads();
    const short8 aq = *(const short8*)&Qs[wave * 16 + fr][fk * 8];

    float m[4], l[4];
    float4v o0, o1;
#pragma unroll
    for (int r = 0; r < 4; r++) { m[r] = -3.0e38f; l[r] = 0.f; o0[r] = 0.f; o1[r] = 0.f; }

    const int vd = tid >> 3, vpart = tid & 7;   // V staging: 32 rows x 8 chunks
    for (int kb = kv0; kb < kv1; kb += 64) {
        __syncthreads();
        {
            const int gk = kb + srow;
            if (gk < kv1)
                *(short8*)&Ks[srow][scs * 8] =
                    *(const short8*)&Kbf[(size_t)gk * EDIM + h * HDIM + scs * 8];
            else {
                short8 z = {0,0,0,0,0,0,0,0};
                *(short8*)&Ks[srow][scs * 8] = z;
            }
            const unsigned short* vrow = VbfT + (size_t)(h * HDIM + vd) * VTROW;
            const int base = kb + vpart * 8;
            if (base + 8 <= kv1) {
                *(short8*)&Vt[vd][vpart * 8] = *(const short8*)&vrow[base];
            } else {
#pragma unroll
                for (int j = 0; j < 8; j++)
                    Vt[vd][vpart * 8 + j] = (base + j < kv1) ? vrow[base + j] : 0;
            }
        }
        __syncthreads();
        float4v s[4];
#pragma unroll
        for (int t = 0; t < 4; t++) {
            const short8 bk = *(const short8*)&Ks[t * 16 + fr][fk * 8];
            float4v z; z[0] = 0.f; z[1] = 0.f; z[2] = 0.f; z[3] = 0.f;
            s[t] = __builtin_amdgcn_mfma_f32_16x16x32_bf16(aq, bk, z, 0, 0, 0);
        }
        if (kb + 64 > kv1) {   // partial tile: mask invalid kv columns
#pragma unroll
            for (int t = 0; t < 4; t++) {
                const int colg = kb + t * 16 + fr;
                if (colg >= kv1) { s[t][0] = -3.0e38f; s[t][1] = -3.0e38f;
                                   s[t][2] = -3.0e38f; s[t][3] = -3.0e38f; }
            }
        }
        float cand[4];
#pragma unroll
        for (int r = 0; r < 4; r++)
            cand[r] = fmaxf(fmaxf(s[0][r], s[1][r]), fmaxf(s[2][r], s[3][r]));
#pragma unroll
        for (int off = 1; off < 16; off <<= 1)
#pragma unroll
            for (int r = 0; r < 4; r++)
                cand[r] = fmaxf(cand[r], __shfl_xor(cand[r], off));
        float corr[4];
#pragma unroll
        for (int r = 0; r < 4; r++) {
            const float mn = fmaxf(m[r], cand[r]);
            corr[r] = __expf(m[r] - mn);
            m[r] = mn;
        }
        float psum[4];
#pragma unroll
        for (int r = 0; r < 4; r++) psum[r] = 0.f;
#pragma unroll
        for (int t = 0; t < 4; t++)
#pragma unroll
            for (int r = 0; r < 4; r++) {
                const float p = __expf(s[t][r] - m[r]);
                psum[r] += p;
                Ps[wave][fk * 4 + r][t * 16 + fr] = f2bf(p);
            }
#pragma unroll
        for (int off = 1; off < 16; off <<= 1)
#pragma unroll
            for (int r = 0; r < 4; r++)
                psum[r] += __shfl_xor(psum[r], off);
#pragma unroll
        for (int r = 0; r < 4; r++) {
            l[r] = l[r] * corr[r] + psum[r];
            o0[r] *= corr[r];
            o1[r] *= corr[r];
        }
        const short8 ap0 = *(const short8*)&Ps[wave][fr][fk * 8];
        const short8 ap1 = *(const short8*)&Ps[wave][fr][32 + fk * 8];
        {
            const short8 bv0 = *(const short8*)&Vt[fr][fk * 8];
            const short8 bv1 = *(const short8*)&Vt[fr][32 + fk * 8];
            o0 = __builtin_amdgcn_mfma_f32_16x16x32_bf16(ap0, bv0, o0, 0, 0, 0);
            o0 = __builtin_amdgcn_mfma_f32_16x16x32_bf16(ap1, bv1, o0, 0, 0, 0);
        }
        {
            const short8 bv0 = *(const short8*)&Vt[16 + fr][fk * 8];
            const short8 bv1 = *(const short8*)&Vt[16 + fr][32 + fk * 8];
            o1 = __builtin_amdgcn_mfma_f32_16x16x32_bf16(ap0, bv0, o1, 0, 0, 0);
            o1 = __builtin_amdgcn_mfma_f32_16x16x32_bf16(ap1, bv1, o1, 0, 0, 0);
        }
    }
#pragma unroll
    for (int r = 0; r < 4; r++) {
        const int q = q0 + wave * 16 + fk * 4 + r;
        if (q < NPIX) {
            const size_t pi = ((size_t)chunk * NPIX + q) * NHEADS + h;
            pacc[pi * 32 + fr]      = o0[r];
            pacc[pi * 32 + 16 + fr] = o1[r];
            if (fr == 0) { pml[pi * 2] = m[r]; pml[pi * 2 + 1] = l[r]; }
        }
    }
}

// ---------------- merge split-KV partials (bf16 output for ta_out GEMM) -------------
__global__ __launch_bounds__(256) void mha_merge_k(const float* __restrict__ pacc,
                                                   const float* __restrict__ pml,
                                                   unsigned short* __restrict__ O)
{
    const int q = blockIdx.x;
    const int tid = threadIdx.x;
    const int h = tid >> 5, d = tid & 31;
    float ms[NCHUNK], ls[NCHUNK];
    float gm = -3.0e38f;
#pragma unroll
    for (int c = 0; c < NCHUNK; c++) {
        const size_t pi = ((size_t)c * NPIX + q) * NHEADS + h;
        ms[c] = pml[pi * 2];
        ls[c] = pml[pi * 2 + 1];
        gm = fmaxf(gm, ms[c]);
    }
    float gl = 0.f, s = 0.f;
#pragma unroll
    for (int c = 0; c < NCHUNK; c++) {
        const size_t pi = ((size_t)c * NPIX + q) * NHEADS + h;
        float w = __expf(ms[c] - gm);
        gl += ls[c] * w;
        s  += pacc[pi * 32 + d] * w;
    }
    O[(size_t)q * EDIM + h * HDIM + d] = f2bf(s / gl);
}

// =====================================================================================
extern "C" void kernel_launch(void* const* d_in, const int* in_sizes, int n_in,
                              void* d_out, int out_size, void* d_ws, size_t ws_size,
                              hipStream_t stream)
{
    const float* bev_emb  = (const float*)d_in[0];
    const float* bev_pose = (const float*)d_in[1];
    const float* ta_in_w  = (const float*)d_in[2];
    const float* ta_in_b  = (const float*)d_in[3];
    const float* ta_out_w = (const float*)d_in[4];
    const float* ta_out_b = (const float*)d_in[5];
    const float* so_w     = (const float*)d_in[6];
    const float* so_b     = (const float*)d_in[7];
    const float* aw_w     = (const float*)d_in[8];
    const float* aw_b     = (const float*)d_in[9];
    const float* vp_w     = (const float*)d_in[10];
    const float* vp_b     = (const float*)d_in[11];
    const float* op_w     = (const float*)d_in[12];
    const float* op_b     = (const float*)d_in[13];
    const float* ffn_w1   = (const float*)d_in[14];
    const float* ffn_b1   = (const float*)d_in[15];
    const float* ffn_w2   = (const float*)d_in[16];
    const float* ffn_b2   = (const float*)d_in[17];
    const float* n1_g     = (const float*)d_in[18];
    const float* n1_b     = (const float*)d_in[19];
    const float* n2_g     = (const float*)d_in[20];
    const float* n2_b     = (const float*)d_in[21];
    const float* n3_g     = (const float*)d_in[22];
    const float* n3_b     = (const float*)d_in[23];
    const float* feat0    = (const float*)d_in[24];
    const float* feat1    = (const float*)d_in[25];
    const float* feat2    = (const float*)d_in[26];
    const float* l2i      = (const float*)d_in[27];
    const float* ego      = (const float*)d_in[28];

    float* w = (float*)d_ws;
    float* bev_cur  = w + 16384;
    float* bev_prev = bev_cur  + 640000;
    float* qin      = bev_prev + 640000;    // featT alias base
    float* kin      = qin      + 640000;    // ffn_h alias
    float* prev_al  = kin      + 640000;
    float* Qb       = prev_al  + 640000;
    float* Kb       = Qb       + 640000;
    float* Vb       = Kb       + 640000;
    float* attn_pre = Vb       + 640000;
    float* attn_o   = attn_pre + 640000;
    float* off_buf  = attn_o   + 640000;    // 2500*288 (so|aw raw)
    float* aw_raw   = off_buf  + 480000;    // (span)
    float* aw_soft  = aw_raw   + 240000;    // (unused)
    float* Sm       = aw_soft  + 240000;    // (unused)
    float* vproj    = Sm       + 640000;    // 6*8400*256
    float* Sbuf     = Qb;                   // alias (10000*256)
    float* ffn_h    = kin;                  // alias span (bf16 use)
    float* pacc     = vproj;                // alias: vproj region free during MHA
    float* pml      = vproj + (size_t)NCHUNK * NPIX * NHEADS * 32;
    unsigned short* featT = (unsigned short*)qin;   // bf16 alias, dead after vproj GEMM
    unsigned short* Qbf  = (unsigned short*)attn_o;            // 640000 ushorts
    unsigned short* Kbf  = Qbf + 640000;                       // 640000 ushorts
    unsigned short* VbfT = (unsigned short*)off_buf;           // 256*2504 = 641024
    unsigned short* attn_pre_bf = (unsigned short*)attn_pre;   // bf16 attn_pre
    unsigned short* ffn_hbf = (unsigned short*)ffn_h;          // bf16 ffn hidden
    (void)aw_raw; (void)aw_soft; (void)Sm; (void)Qb; (void)Kb; (void)Vb;

    auto GEMM = [&](const float* A, const float* Wp, const float* bias, float* C,
                    int M, int N, int K, int act) {
        dim3 g((N + 63) / 64, (M + 63) / 64);
        if (act)
            gemm64_k<1, 0><<<g, 256, 0, stream>>>(A, nullptr, Wp, bias, C, M, N, K,
                                                  0, 0, 0, 0);
        else
            gemm64_k<0, 0><<<g, 256, 0, stream>>>(A, nullptr, Wp, bias, C, M, N, K,
                                                  0, 0, 0, 0);
    };

    for (int t = 0; t < 2; t++) {
        // layer input (`bev`) is always bev_emb; only prev carries state across t.
        const float* cur = bev_emb;
        if (t > 0) {
            // temporal align (4x4 inverse fused per block)
            talign_k<<<NPIX, 256, 0, stream>>>(bev_prev, ego + (size_t)t * 16, prev_al);
            // merged QKV projection: one launch, z selects Q/K/V (480 blocks co-run)
            gemm_qkv_k<<<dim3(4, 40, 3), 256, 0, stream>>>(
                bev_emb, prev_al, bev_pose, ta_in_w, ta_in_b, Qbf, Kbf, VbfT);
            mha_mfma_k<<<dim3((NPIX + 63) / 64, NHEADS, NCHUNK), 256, 0, stream>>>(
                Qbf, Kbf, VbfT, pacc, pml);
            mha_merge_k<<<NPIX, 256, 0, stream>>>(pacc, pml, attn_pre_bf);
            // ta_out projection from bf16 attention output
            gemm64b_k<<<dim3(4, 40), 256, 0, stream>>>(
                attn_pre_bf, ta_out_w, ta_out_b, attn_o, NPIX, EDIM, EDIM, 0, 0);
            resid_ln_k<0, 0><<<NPIX, 256, 0, stream>>>(
                bev_emb, attn_o, nullptr, nullptr, 0, n1_g, n1_b, bev_cur);
            cur = bev_cur;
        }
        // ---- spatial cross-attention: merged feat transpose, then vproj+soaw merged -
        transpose_feat_all_k<<<dim3(263, 8, 6), 256, 0, stream>>>(
            feat0, feat1, feat2, t, featT);
        gemm_vs_k<<<dim3(5, 132, 7), 256, 0, stream>>>(
            featT, vp_w, vp_b, vproj, cur, bev_pose, so_w, aw_w, so_b, aw_b, off_buf);
        // sampling: uv + aw-softmax computed in-block from raw off_buf
        spatial_sample_k<<<NQTOT, 256, 0, stream>>>(vproj, off_buf, l2i, t, Sbuf);
        // op projection with fused Z-reduce A-staging; sfac recomputed inline
        gemm_op_k<<<dim3(4, 40), 256, 0, stream>>>(Sbuf, l2i, t, op_w, attn_o);
        // LN2 recomputes vbm inline (op_b folded via cvec*svbm)
        resid_ln_k<0, 1><<<NPIX, 256, 0, stream>>>(
            cur, attn_o, op_b, l2i, t, n2_g, n2_b, bev_cur);
        // FFN: w1 -> bf16 hidden (ReLU fused), w2 from bf16
        gemm64o_k<1, 0><<<dim3(8, 40), 256, 0, stream>>>(
            bev_cur, nullptr, ffn_w1, ffn_b1, ffn_hbf, NPIX, FFND, EDIM);
        gemm64b_k<<<dim3(4, 40), 256, 0, stream>>>(
            ffn_hbf, ffn_w2, ffn_b2, attn_o, NPIX, EDIM, FFND, 0, 0);
        // t=0: LN -> bev_prev; t=1: LN writes TRANSPOSED final output directly
        if (t == 0)
            resid_ln_k<0, 0><<<NPIX, 256, 0, stream>>>(
                bev_cur, attn_o, nullptr, nullptr, 0, n3_g, n3_b, bev_prev);
        else
            resid_ln_k<1, 0><<<NPIX, 256, 0, stream>>>(
                bev_cur, attn_o, nullptr, nullptr, 0, n3_g, n3_b, (float*)d_out);
    }
}

// Round 26
// 389.881 us; speedup vs baseline: 1.0228x; 1.0228x over previous
//
#include <hip/hip_runtime.h>
#include <hip/hip_bf16.h>

#define NPIX   2500
#define EDIM   256
#define NHEADS 8
#define HDIM   32
#define NLVLS  3
#define NPTS   4
#define NZ     4
#define NCAMS  6
#define NQTOT  10000   // NPIX*NZ
#define NVAL   8400    // 6400+1600+400 value positions per cam
#define FFND   512
#define NCHUNK 10
#define KVCH   250     // NPIX / NCHUNK
#define VTROW  2504    // VbfT row stride (ushorts): 5008B, 16B-aligned

typedef __attribute__((ext_vector_type(8))) short short8;
typedef __attribute__((ext_vector_type(4))) float float4v;

__device__ __forceinline__ void level_params(int l, int& H, int& W, int& st) {
    if (l == 0)      { H = 64; W = 100; st = 0;    }
    else if (l == 1) { H = 32; W = 50;  st = 6400; }
    else             { H = 16; W = 25;  st = 8000; }
}

__device__ __forceinline__ unsigned short f2bf(float x) {
    unsigned int u = __builtin_bit_cast(unsigned int, x);
    return (unsigned short)((u + 0x7fffu + ((u >> 16) & 1u)) >> 16);
}

// ------ merged feat transpose (all 3 levels, one launch): F[e][p] f32 -> featT bf16 --
__global__ __launch_bounds__(256) void transpose_feat_all_k(const float* __restrict__ feat0,
                                                            const float* __restrict__ feat1,
                                                            const float* __restrict__ feat2,
                                                            int t,
                                                            unsigned short* __restrict__ featT)
{
    const int cam = blockIdx.z;
    const int bx = blockIdx.x;
    const float* feat; int HW, lvl_off, p0;
    if (bx < 200)      { feat = feat0; HW = 6400; lvl_off = 0;    p0 = bx * 32;         }
    else if (bx < 250) { feat = feat1; HW = 1600; lvl_off = 6400; p0 = (bx - 200) * 32; }
    else               { feat = feat2; HW = 400;  lvl_off = 8000; p0 = (bx - 250) * 32; }
    const float* F = feat + (size_t)(t * NCAMS + cam) * EDIM * HW;
    unsigned short* T = featT + (size_t)cam * NVAL * EDIM;
    __shared__ float tile[32][33];
    const int e0 = blockIdx.y * 32;
    const int tp = threadIdx.x & 31, tr = threadIdx.x >> 5;
#pragma unroll
    for (int i = 0; i < 4; i++) {
        int e = e0 + tr + i * 8;
        int p = p0 + tp;
        tile[tr + i * 8][tp] = (p < HW) ? F[(size_t)e * HW + p] : 0.f;
    }
    __syncthreads();
#pragma unroll
    for (int i = 0; i < 4; i++) {
        int p = p0 + tr + i * 8;
        int e = e0 + tp;
        if (p < HW) T[(size_t)(lvl_off + p) * EDIM + e] = f2bf(tile[tp][tr + i * 8]);
    }
}

// ---------------- MFMA GEMM 64x64 (f32 A; f32 out) ----------------------------------
template<int ACT, int ADD>
__global__ __launch_bounds__(256) void gemm64_k(const float* __restrict__ A,
                                                const float* __restrict__ A2,
                                                const float* __restrict__ W,
                                                const float* __restrict__ bias,
                                                float* __restrict__ C,
                                                int M, int N, int K,
                                                size_t a_bs, size_t w_bs,
                                                size_t b_bs, size_t c_bs)
{
    __shared__ unsigned short As[64][44];
    __shared__ unsigned short Ws[64][44];
    const int m0 = blockIdx.y * 64;
    const int n0 = blockIdx.x * 64;
    const int tid = threadIdx.x;
    const float* Af = A + blockIdx.z * a_bs;
    const float* Wf = W + blockIdx.z * w_bs;
    const float* Bf = bias ? bias + blockIdx.z * b_bs : nullptr;
    float* Cb = C + blockIdx.z * c_bs;
    const int wave = tid >> 6, lane = tid & 63;
    const int wr = wave >> 1, wc = wave & 1;
    const int fr = lane & 15, fk = lane >> 4;
    float4v acc[2][2];
#pragma unroll
    for (int mi = 0; mi < 2; mi++)
#pragma unroll
        for (int ni = 0; ni < 2; ni++) { acc[mi][ni][0] = 0.f; acc[mi][ni][1] = 0.f;
                                         acc[mi][ni][2] = 0.f; acc[mi][ni][3] = 0.f; }
    const int srow = tid >> 2, sk = (tid & 3) * 8;
    for (int k0 = 0; k0 < K; k0 += 32) {
        unsigned short tmp[8];
        {
            const int gr = m0 + srow;
            if (gr < M) {
                const float* src = Af + (size_t)gr * K + k0 + sk;
                if (ADD) {
                    const float* src2 = A2 + (size_t)gr * K + k0 + sk;
#pragma unroll
                    for (int j = 0; j < 8; j++) tmp[j] = f2bf(src[j] + src2[j]);
                } else {
#pragma unroll
                    for (int j = 0; j < 8; j++) tmp[j] = f2bf(src[j]);
                }
            } else {
#pragma unroll
                for (int j = 0; j < 8; j++) tmp[j] = 0;
            }
            *(short8*)&As[srow][sk] = *(short8*)&tmp[0];
        }
        {
            const int gw = n0 + srow;
            if (gw < N) {
                const float* src = Wf + (size_t)gw * K + k0 + sk;
#pragma unroll
                for (int j = 0; j < 8; j++) tmp[j] = f2bf(src[j]);
            } else {
#pragma unroll
                for (int j = 0; j < 8; j++) tmp[j] = 0;
            }
            *(short8*)&Ws[srow][sk] = *(short8*)&tmp[0];
        }
        __syncthreads();
        short8 af[2], bfr[2];
#pragma unroll
        for (int mi = 0; mi < 2; mi++)
            af[mi] = *(const short8*)&As[wr * 32 + mi * 16 + fr][fk * 8];
#pragma unroll
        for (int ni = 0; ni < 2; ni++)
            bfr[ni] = *(const short8*)&Ws[wc * 32 + ni * 16 + fr][fk * 8];
#pragma unroll
        for (int mi = 0; mi < 2; mi++)
#pragma unroll
            for (int ni = 0; ni < 2; ni++)
                acc[mi][ni] = __builtin_amdgcn_mfma_f32_16x16x32_bf16(
                    af[mi], bfr[ni], acc[mi][ni], 0, 0, 0);
        __syncthreads();
    }
#pragma unroll
    for (int mi = 0; mi < 2; mi++)
#pragma unroll
        for (int ni = 0; ni < 2; ni++) {
            const int col = n0 + wc * 32 + ni * 16 + fr;
#pragma unroll
            for (int r = 0; r < 4; r++) {
                const int row = m0 + wr * 32 + mi * 16 + fk * 4 + r;
                if (row < M && col < N) {
                    float v = acc[mi][ni][r] + (Bf ? Bf[col] : 0.f);
                    if (ACT) v = fmaxf(v, 0.f);
                    Cb[(size_t)row * N + col] = v;
                }
            }
        }
}

// ---------------- MFMA GEMM 64x64, f32 A -> bf16 OUT (generic M/N/K) -----------------
template<int ACT, int ADD>
__global__ __launch_bounds__(256) void gemm64o_k(const float* __restrict__ A,
                                                 const float* __restrict__ A2,
                                                 const float* __restrict__ W,
                                                 const float* __restrict__ bias,
                                                 unsigned short* __restrict__ C,
                                                 int M, int N, int K)
{
    __shared__ unsigned short As[64][44];
    __shared__ unsigned short Ws[64][44];
    const int m0 = blockIdx.y * 64;
    const int n0 = blockIdx.x * 64;
    const int tid = threadIdx.x;
    const int wave = tid >> 6, lane = tid & 63;
    const int wr = wave >> 1, wc = wave & 1;
    const int fr = lane & 15, fk = lane >> 4;
    float4v acc[2][2];
#pragma unroll
    for (int mi = 0; mi < 2; mi++)
#pragma unroll
        for (int ni = 0; ni < 2; ni++) { acc[mi][ni][0] = 0.f; acc[mi][ni][1] = 0.f;
                                         acc[mi][ni][2] = 0.f; acc[mi][ni][3] = 0.f; }
    const int srow = tid >> 2, sk = (tid & 3) * 8;
    for (int k0 = 0; k0 < K; k0 += 32) {
        unsigned short tmp[8];
        {
            const int gr = m0 + srow;
            if (gr < M) {
                const float* src = A + (size_t)gr * K + k0 + sk;
                if (ADD) {
                    const float* src2 = A2 + (size_t)gr * K + k0 + sk;
#pragma unroll
                    for (int j = 0; j < 8; j++) tmp[j] = f2bf(src[j] + src2[j]);
                } else {
#pragma unroll
                    for (int j = 0; j < 8; j++) tmp[j] = f2bf(src[j]);
                }
            } else {
#pragma unroll
                for (int j = 0; j < 8; j++) tmp[j] = 0;
            }
            *(short8*)&As[srow][sk] = *(short8*)&tmp[0];
        }
        {
            const int gw = n0 + srow;
            if (gw < N) {
                const float* src = W + (size_t)gw * K + k0 + sk;
#pragma unroll
                for (int j = 0; j < 8; j++) tmp[j] = f2bf(src[j]);
            } else {
#pragma unroll
                for (int j = 0; j < 8; j++) tmp[j] = 0;
            }
            *(short8*)&Ws[srow][sk] = *(short8*)&tmp[0];
        }
        __syncthreads();
        short8 af[2], bfr[2];
#pragma unroll
        for (int mi = 0; mi < 2; mi++)
            af[mi] = *(const short8*)&As[wr * 32 + mi * 16 + fr][fk * 8];
#pragma unroll
        for (int ni = 0; ni < 2; ni++)
            bfr[ni] = *(const short8*)&Ws[wc * 32 + ni * 16 + fr][fk * 8];
#pragma unroll
        for (int mi = 0; mi < 2; mi++)
#pragma unroll
            for (int ni = 0; ni < 2; ni++)
                acc[mi][ni] = __builtin_amdgcn_mfma_f32_16x16x32_bf16(
                    af[mi], bfr[ni], acc[mi][ni], 0, 0, 0);
        __syncthreads();
    }
#pragma unroll
    for (int mi = 0; mi < 2; mi++)
#pragma unroll
        for (int ni = 0; ni < 2; ni++) {
            const int col = n0 + wc * 32 + ni * 16 + fr;
#pragma unroll
            for (int r = 0; r < 4; r++) {
                const int row = m0 + wr * 32 + mi * 16 + fk * 4 + r;
                if (row < M && col < N) {
                    float v = acc[mi][ni][r] + (bias ? bias[col] : 0.f);
                    if (ACT) v = fmaxf(v, 0.f);
                    C[(size_t)row * N + col] = f2bf(v);
                }
            }
        }
}

// ---------- merged QKV GEMM: z=0 -> Qbf (scaled), z=1 -> Kbf, z=2 -> VbfT (trans) ----
__global__ __launch_bounds__(256) void gemm_qkv_k(const float* __restrict__ bev_emb,
                                                  const float* __restrict__ prev_al,
                                                  const float* __restrict__ bev_pose,
                                                  const float* __restrict__ ta_in_w,
                                                  const float* __restrict__ ta_in_b,
                                                  unsigned short* __restrict__ Qbf,
                                                  unsigned short* __restrict__ Kbf,
                                                  unsigned short* __restrict__ VbfT)
{
    __shared__ unsigned short As[64][44];
    __shared__ unsigned short Ws[64][44];
    const int z = blockIdx.z;
    const float* A    = (z == 0) ? bev_emb : prev_al;
    const float* A2   = (z == 2) ? nullptr : bev_pose;
    const float* W    = ta_in_w + (size_t)z * EDIM * EDIM;
    const float* bias = ta_in_b + z * EDIM;
    const float oscale = (z == 0) ? 0.17677669529663689f : 1.0f;
    unsigned short* C = (z == 0) ? Qbf : (z == 1) ? Kbf : VbfT;
    const int m0 = blockIdx.y * 64;
    const int n0 = blockIdx.x * 64;
    const int tid = threadIdx.x;
    const int wave = tid >> 6, lane = tid & 63;
    const int wr = wave >> 1, wc = wave & 1;
    const int fr = lane & 15, fk = lane >> 4;
    float4v acc[2][2];
#pragma unroll
    for (int mi = 0; mi < 2; mi++)
#pragma unroll
        for (int ni = 0; ni < 2; ni++) { acc[mi][ni][0] = 0.f; acc[mi][ni][1] = 0.f;
                                         acc[mi][ni][2] = 0.f; acc[mi][ni][3] = 0.f; }
    const int srow = tid >> 2, sk = (tid & 3) * 8;
    for (int k0 = 0; k0 < EDIM; k0 += 32) {
        unsigned short tmp[8];
        {
            const int gr = m0 + srow;
            if (gr < NPIX) {
                const float* src = A + (size_t)gr * EDIM + k0 + sk;
                if (A2) {
                    const float* src2 = A2 + (size_t)gr * EDIM + k0 + sk;
#pragma unroll
                    for (int j = 0; j < 8; j++) tmp[j] = f2bf(src[j] + src2[j]);
                } else {
#pragma unroll
                    for (int j = 0; j < 8; j++) tmp[j] = f2bf(src[j]);
                }
            } else {
#pragma unroll
                for (int j = 0; j < 8; j++) tmp[j] = 0;
            }
            *(short8*)&As[srow][sk] = *(short8*)&tmp[0];
        }
        {
            const float* src = W + (size_t)(n0 + srow) * EDIM + k0 + sk;
#pragma unroll
            for (int j = 0; j < 8; j++) tmp[j] = f2bf(src[j]);
            *(short8*)&Ws[srow][sk] = *(short8*)&tmp[0];
        }
        __syncthreads();
        short8 af[2], bfr[2];
#pragma unroll
        for (int mi = 0; mi < 2; mi++)
            af[mi] = *(const short8*)&As[wr * 32 + mi * 16 + fr][fk * 8];
#pragma unroll
        for (int ni = 0; ni < 2; ni++)
            bfr[ni] = *(const short8*)&Ws[wc * 32 + ni * 16 + fr][fk * 8];
#pragma unroll
        for (int mi = 0; mi < 2; mi++)
#pragma unroll
            for (int ni = 0; ni < 2; ni++)
                acc[mi][ni] = __builtin_amdgcn_mfma_f32_16x16x32_bf16(
                    af[mi], bfr[ni], acc[mi][ni], 0, 0, 0);
        __syncthreads();
    }
#pragma unroll
    for (int mi = 0; mi < 2; mi++)
#pragma unroll
        for (int ni = 0; ni < 2; ni++) {
            const int col = n0 + wc * 32 + ni * 16 + fr;
#pragma unroll
            for (int r = 0; r < 4; r++) {
                const int row = m0 + wr * 32 + mi * 16 + fk * 4 + r;
                if (row < NPIX) {
                    const float v = (acc[mi][ni][r] + bias[col]) * oscale;
                    if (z == 2)
                        C[(size_t)col * VTROW + row] = f2bf(v);
                    else
                        C[(size_t)row * EDIM + col] = f2bf(v);
                }
            }
        }
}

// ---------------- MFMA GEMM 64x64, bf16 A; nullable bias ----------------------------
__global__ __launch_bounds__(256) void gemm64b_k(const unsigned short* __restrict__ A,
                                                 const float* __restrict__ W,
                                                 const float* __restrict__ bias,
                                                 float* __restrict__ C,
                                                 int M, int N, int K,
                                                 size_t a_bs, size_t c_bs)
{
    __shared__ unsigned short As[64][44];
    __shared__ unsigned short Ws[64][44];
    const int m0 = blockIdx.y * 64;
    const int n0 = blockIdx.x * 64;
    const int tid = threadIdx.x;
    const unsigned short* Af = A + blockIdx.z * a_bs;
    float* Cb = C + blockIdx.z * c_bs;
    const int wave = tid >> 6, lane = tid & 63;
    const int wr = wave >> 1, wc = wave & 1;
    const int fr = lane & 15, fk = lane >> 4;
    float4v acc[2][2];
#pragma unroll
    for (int mi = 0; mi < 2; mi++)
#pragma unroll
        for (int ni = 0; ni < 2; ni++) { acc[mi][ni][0] = 0.f; acc[mi][ni][1] = 0.f;
                                         acc[mi][ni][2] = 0.f; acc[mi][ni][3] = 0.f; }
    const int srow = tid >> 2, sk = (tid & 3) * 8;
    for (int k0 = 0; k0 < K; k0 += 32) {
        {
            const int gr = m0 + srow;
            if (gr < M) {
                *(short8*)&As[srow][sk] =
                    *(const short8*)&Af[(size_t)gr * K + k0 + sk];
            } else {
                short8 z = {0,0,0,0,0,0,0,0};
                *(short8*)&As[srow][sk] = z;
            }
        }
        {
            unsigned short tmp[8];
            const int gw = n0 + srow;
            if (gw < N) {
                const float* src = W + (size_t)gw * K + k0 + sk;
#pragma unroll
                for (int j = 0; j < 8; j++) tmp[j] = f2bf(src[j]);
            } else {
#pragma unroll
                for (int j = 0; j < 8; j++) tmp[j] = 0;
            }
            *(short8*)&Ws[srow][sk] = *(short8*)&tmp[0];
        }
        __syncthreads();
        short8 af[2], bfr[2];
#pragma unroll
        for (int mi = 0; mi < 2; mi++)
            af[mi] = *(const short8*)&As[wr * 32 + mi * 16 + fr][fk * 8];
#pragma unroll
        for (int ni = 0; ni < 2; ni++)
            bfr[ni] = *(const short8*)&Ws[wc * 32 + ni * 16 + fr][fk * 8];
#pragma unroll
        for (int mi = 0; mi < 2; mi++)
#pragma unroll
            for (int ni = 0; ni < 2; ni++)
                acc[mi][ni] = __builtin_amdgcn_mfma_f32_16x16x32_bf16(
                    af[mi], bfr[ni], acc[mi][ni], 0, 0, 0);
        __syncthreads();
    }
#pragma unroll
    for (int mi = 0; mi < 2; mi++)
#pragma unroll
        for (int ni = 0; ni < 2; ni++) {
            const int col = n0 + wc * 32 + ni * 16 + fr;
#pragma unroll
            for (int r = 0; r < 4; r++) {
                const int row = m0 + wr * 32 + mi * 16 + fk * 4 + r;
                if (row < M && col < N)
                    Cb[(size_t)row * N + col] = acc[mi][ni][r] + (bias ? bias[col] : 0.f);
            }
        }
}

// ------ merged vproj (z=0..5, bf16 A) + so/aw (z=6, f32 A+A2) GEMM, one launch -------
__global__ __launch_bounds__(256) void gemm_vs_k(const unsigned short* __restrict__ featT,
                                                 const float* __restrict__ vp_w,
                                                 const float* __restrict__ vp_b,
                                                 float* __restrict__ vproj,
                                                 const float* __restrict__ Aso,
                                                 const float* __restrict__ A2so,
                                                 const float* __restrict__ Wso,
                                                 const float* __restrict__ Waw,
                                                 const float* __restrict__ Bso,
                                                 const float* __restrict__ Baw,
                                                 float* __restrict__ Cso)
{
    const int z = blockIdx.z;
    const bool so = (z == 6);
    if (!so && blockIdx.x >= 4) return;   // vproj: N=256 -> 4 col tiles
    if (so && blockIdx.y >= 40) return;   // soaw: M=2500 -> 40 row tiles
    __shared__ unsigned short As[64][44];
    __shared__ unsigned short Ws[64][44];
    const int m0 = blockIdx.y * 64;
    const int n0 = blockIdx.x * 64;
    const int tid = threadIdx.x;
    const int wave = tid >> 6, lane = tid & 63;
    const int wr = wave >> 1, wc = wave & 1;
    const int fr = lane & 15, fk = lane >> 4;
    const unsigned short* Af = featT + (size_t)z * NVAL * EDIM;  // z<6 only
    const int M = so ? NPIX : NVAL;
    float4v acc[2][2];
#pragma unroll
    for (int mi = 0; mi < 2; mi++)
#pragma unroll
        for (int ni = 0; ni < 2; ni++) { acc[mi][ni][0] = 0.f; acc[mi][ni][1] = 0.f;
                                         acc[mi][ni][2] = 0.f; acc[mi][ni][3] = 0.f; }
    const int srow = tid >> 2, sk = (tid & 3) * 8;
    for (int k0 = 0; k0 < EDIM; k0 += 32) {
        unsigned short tmp[8];
        {
            const int gr = m0 + srow;
            if (so) {
                if (gr < NPIX) {
                    const float* src  = Aso  + (size_t)gr * EDIM + k0 + sk;
                    const float* src2 = A2so + (size_t)gr * EDIM + k0 + sk;
#pragma unroll
                    for (int j = 0; j < 8; j++) tmp[j] = f2bf(src[j] + src2[j]);
                } else {
#pragma unroll
                    for (int j = 0; j < 8; j++) tmp[j] = 0;
                }
                *(short8*)&As[srow][sk] = *(short8*)&tmp[0];
            } else {
                if (gr < NVAL) {
                    *(short8*)&As[srow][sk] =
                        *(const short8*)&Af[(size_t)gr * EDIM + k0 + sk];
                } else {
                    short8 zr = {0,0,0,0,0,0,0,0};
                    *(short8*)&As[srow][sk] = zr;
                }
            }
        }
        {
            const int gw = n0 + srow;
            const float* src;
            if (so)
                src = (gw < 192) ? Wso + (size_t)gw * EDIM + k0 + sk
                    : (gw < 288) ? Waw + (size_t)(gw - 192) * EDIM + k0 + sk
                                 : nullptr;
            else
                src = vp_w + (size_t)gw * EDIM + k0 + sk;
            if (src) {
#pragma unroll
                for (int j = 0; j < 8; j++) tmp[j] = f2bf(src[j]);
            } else {
#pragma unroll
                for (int j = 0; j < 8; j++) tmp[j] = 0;
            }
            *(short8*)&Ws[srow][sk] = *(short8*)&tmp[0];
        }
        __syncthreads();
        short8 af[2], bfr[2];
#pragma unroll
        for (int mi = 0; mi < 2; mi++)
            af[mi] = *(const short8*)&As[wr * 32 + mi * 16 + fr][fk * 8];
#pragma unroll
        for (int ni = 0; ni < 2; ni++)
            bfr[ni] = *(const short8*)&Ws[wc * 32 + ni * 16 + fr][fk * 8];
#pragma unroll
        for (int mi = 0; mi < 2; mi++)
#pragma unroll
            for (int ni = 0; ni < 2; ni++)
                acc[mi][ni] = __builtin_amdgcn_mfma_f32_16x16x32_bf16(
                    af[mi], bfr[ni], acc[mi][ni], 0, 0, 0);
        __syncthreads();
    }
#pragma unroll
    for (int mi = 0; mi < 2; mi++)
#pragma unroll
        for (int ni = 0; ni < 2; ni++) {
            const int col = n0 + wc * 32 + ni * 16 + fr;
#pragma unroll
            for (int r = 0; r < 4; r++) {
                const int row = m0 + wr * 32 + mi * 16 + fk * 4 + r;
                if (row < M) {
                    if (so) {
                        if (col < 288) {
                            const float b = (col < 192) ? Bso[col] : Baw[col - 192];
                            Cso[(size_t)row * 288 + col] = acc[mi][ni][r] + b;
                        }
                    } else {
                        vproj[((size_t)z * NVAL + row) * EDIM + col] =
                            acc[mi][ni][r] + vp_b[col];
                    }
                }
            }
        }
}

// ------ op-proj GEMM with fused Z-reduce A-staging: A = sum_z S[pix*4+iz]*sfac ------
__global__ __launch_bounds__(256) void gemm_op_k(const float* __restrict__ S,
                                                 const float* __restrict__ validn,
                                                 const float* __restrict__ W,
                                                 float* __restrict__ C)
{
    __shared__ unsigned short As[64][44];
    __shared__ unsigned short Ws[64][44];
    __shared__ float sfac[256];
    const int m0 = blockIdx.y * 64;
    const int n0 = blockIdx.x * 64;
    const int tid = threadIdx.x;
    {
        const int idx = m0 * 4 + tid;
        const float vn = (idx < NQTOT) ? validn[idx] : 1.f;
        sfac[tid] = 1.f / fmaxf(vn, 1.f);
    }
    __syncthreads();
    const int wave = tid >> 6, lane = tid & 63;
    const int wr = wave >> 1, wc = wave & 1;
    const int fr = lane & 15, fk = lane >> 4;
    float4v acc[2][2];
#pragma unroll
    for (int mi = 0; mi < 2; mi++)
#pragma unroll
        for (int ni = 0; ni < 2; ni++) { acc[mi][ni][0] = 0.f; acc[mi][ni][1] = 0.f;
                                         acc[mi][ni][2] = 0.f; acc[mi][ni][3] = 0.f; }
    const int srow = tid >> 2, sk = (tid & 3) * 8;
    for (int k0 = 0; k0 < EDIM; k0 += 32) {
        unsigned short tmp[8];
        {
            const int gr = m0 + srow;
            if (gr < NPIX) {
                float sum[8];
#pragma unroll
                for (int j = 0; j < 8; j++) sum[j] = 0.f;
#pragma unroll
                for (int iz = 0; iz < NZ; iz++) {
                    const float* src = S + ((size_t)(gr * 4 + iz) * EDIM + k0 + sk);
                    const float f = sfac[srow * 4 + iz];
#pragma unroll
                    for (int j = 0; j < 8; j++) sum[j] += src[j] * f;
                }
#pragma unroll
                for (int j = 0; j < 8; j++) tmp[j] = f2bf(sum[j] * 0.25f);
            } else {
#pragma unroll
                for (int j = 0; j < 8; j++) tmp[j] = 0;
            }
            *(short8*)&As[srow][sk] = *(short8*)&tmp[0];
        }
        {
            const float* src = W + (size_t)(n0 + srow) * EDIM + k0 + sk;
#pragma unroll
            for (int j = 0; j < 8; j++) tmp[j] = f2bf(src[j]);
            *(short8*)&Ws[srow][sk] = *(short8*)&tmp[0];
        }
        __syncthreads();
        short8 af[2], bfr[2];
#pragma unroll
        for (int mi = 0; mi < 2; mi++)
            af[mi] = *(const short8*)&As[wr * 32 + mi * 16 + fr][fk * 8];
#pragma unroll
        for (int ni = 0; ni < 2; ni++)
            bfr[ni] = *(const short8*)&Ws[wc * 32 + ni * 16 + fr][fk * 8];
#pragma unroll
        for (int mi = 0; mi < 2; mi++)
#pragma unroll
            for (int ni = 0; ni < 2; ni++)
                acc[mi][ni] = __builtin_amdgcn_mfma_f32_16x16x32_bf16(
                    af[mi], bfr[ni], acc[mi][ni], 0, 0, 0);
        __syncthreads();
    }
#pragma unroll
    for (int mi = 0; mi < 2; mi++)
#pragma unroll
        for (int ni = 0; ni < 2; ni++) {
            const int col = n0 + wc * 32 + ni * 16 + fr;
#pragma unroll
            for (int r = 0; r < 4; r++) {
                const int row = m0 + wr * 32 + mi * 16 + fk * 4 + r;
                if (row < NPIX)
                    C[(size_t)row * EDIM + col] = acc[mi][ni][r];
            }
        }
}

// ---------------- residual + LayerNorm (TRANS=1: write transposed to d_out) ----------
template<int TRANS>
__global__ __launch_bounds__(256) void resid_ln_k(const float* __restrict__ x0,
                                                  const float* __restrict__ x1,
                                                  const float* __restrict__ cvec,
                                                  const float* __restrict__ cscale,
                                                  const float* __restrict__ g,
                                                  const float* __restrict__ bta,
                                                  float* __restrict__ out)
{
    const int row = blockIdx.x, e = threadIdx.x;
    float x = x0[(size_t)row * EDIM + e] + x1[(size_t)row * EDIM + e];
    if (cvec) x += cvec[e] * cscale[row];
    __shared__ float red[256];
    red[e] = x; __syncthreads();
    for (int s = 128; s > 0; s >>= 1) { if (e < s) red[e] += red[e + s]; __syncthreads(); }
    float mean = red[0] * (1.f / 256.f);
    __syncthreads();
    float dx = x - mean;
    red[e] = dx * dx; __syncthreads();
    for (int s = 128; s > 0; s >>= 1) { if (e < s) red[e] += red[e + s]; __syncthreads(); }
    float var = red[0] * (1.f / 256.f);
    const float res = dx * rsqrtf(var + 1e-5f) * g[e] + bta[e];
    if (TRANS)
        out[(size_t)e * NPIX + row] = res;
    else
        out[(size_t)row * EDIM + e] = res;
}

// ------- fused uv precompute + vbm (blocks 0..39) + aw softmax (blocks 40..118) ------
__global__ void uv_aw_k(const float* __restrict__ l2i, int t,
                        const float* __restrict__ raw,
                        float* __restrict__ uvtab,
                        float* __restrict__ validn,
                        float* __restrict__ aw_soft,
                        float* __restrict__ vbm)
{
    if (blockIdx.x < 40) {
        const int n = blockIdx.x * 256 + threadIdx.x;
        if (n >= NQTOT) return;
        const int pix = n >> 2, iz = n & 3;
        const int prow = pix / 50, pcol = pix % 50;
        const float x3 = (pcol + 0.5f) * 4.0f - 60.f;
        const float y3 = (prow + 0.5f) * 2.4f - 60.f;
        const float z3 = (iz + 0.5f) * 2.0f - 4.f;
        int vcount = 0;
        float buf[12];
#pragma unroll
        for (int cam = 0; cam < NCAMS; cam++) {
            const float* Mt = l2i + (size_t)(t * NCAMS + cam) * 16;
            const float p0 = Mt[0] * x3 + Mt[1] * y3 + Mt[2]  * z3 + Mt[3];
            const float p1 = Mt[4] * x3 + Mt[5] * y3 + Mt[6]  * z3 + Mt[7];
            const float p2 = Mt[8] * x3 + Mt[9] * y3 + Mt[10] * z3 + Mt[11];
            const float dd = p2 + 1e-5f;
            const float u = p0 / dd * (1.f / 800.f);
            const float v = p1 / dd * (1.f / 512.f);
            const bool valid = (p2 > 1e-5f) && (u > 0.f) && (u < 1.f) &&
                               (v > 0.f) && (v < 1.f);
            if (valid) vcount++;
            buf[cam * 2]     = valid ? u : -1.f;
            buf[cam * 2 + 1] = v;
        }
#pragma unroll
        for (int j = 0; j < 12; j++) uvtab[(size_t)n * 12 + j] = buf[j];
        validn[n] = (float)vcount;
        // vbm: fraction of valid z-anchors per pixel (4-lane group reduce)
        float ind = (vcount > 0) ? 1.f : 0.f;
        ind += __shfl_xor(ind, 1);
        ind += __shfl_xor(ind, 2);
        if (iz == 0) vbm[pix] = ind * 0.25f;
    } else {
        const int gidx = (blockIdx.x - 40) * 256 + threadIdx.x;
        if (gidx >= NPIX * NHEADS) return;
        const int pix = gidx / NHEADS, h = gidx % NHEADS;
        const float* p = raw + (size_t)pix * 288 + 192 + h * 12;
        float m = -3.0e38f;
#pragma unroll
        for (int j = 0; j < 12; j++) m = fmaxf(m, p[j]);
        float e[12]; float s = 0.f;
#pragma unroll
        for (int j = 0; j < 12; j++) { e[j] = __expf(p[j] - m); s += e[j]; }
        const float inv = 1.f / s;
        float* o = aw_soft + (size_t)pix * 96 + h * 12;
#pragma unroll
        for (int j = 0; j < 12; j++) o[j] = e[j] * inv;
    }
}

// ---------------- deformable sampling v4: uv precomputed; waves split pts ------------
__global__ __launch_bounds__(256) void spatial_sample_k(const float* __restrict__ vproj,
                                                        const float* __restrict__ offb,
                                                        const float* __restrict__ awb,
                                                        const float* __restrict__ uvtab,
                                                        float* __restrict__ S)
{
    const int n = blockIdx.x;
    const int tid = threadIdx.x;
    const int wave = tid >> 6, lane = tid & 63;
    const int ch0 = lane << 2;
    const int h = lane >> 3;
    const int pix = n >> 2;
    __shared__ float soff[192];
    __shared__ float saw[96];
    __shared__ float suv[12];
    __shared__ float red[3][256];
    if (tid < 192) soff[tid] = offb[(size_t)pix * 288 + tid];
    if (tid < 96)  saw[tid]  = awb[(size_t)pix * 96 + tid];
    if (tid >= 192 && tid < 204) suv[tid - 192] = uvtab[(size_t)n * 12 + (tid - 192)];
    __syncthreads();
    float4 acc = make_float4(0.f, 0.f, 0.f, 0.f);
    for (int cam = 0; cam < NCAMS; cam++) {
        const float u = suv[cam * 2];
        if (u < 0.f) continue;
        const float v = suv[cam * 2 + 1];
        const float* vc = vproj + (size_t)cam * NVAL * EDIM + ch0;
        for (int pt = wave; pt < NLVLS * NPTS; pt += 4) {
            const int l = pt >> 2, p = pt & 3;
            int Hl, Wl, st; level_params(l, Hl, Wl, st);
            const int ob = ((h * NLVLS + l) * NPTS + p) * 2;
            const float x = u * (float)Wl + soff[ob]     - 0.5f;
            const float y = v * (float)Hl + soff[ob + 1] - 0.5f;
            const float xf = floorf(x), yf = floorf(y);
            const float wx = x - xf, wy = y - yf;
            const int x0 = (int)xf, y0 = (int)yf;
            const float a = saw[(h * NLVLS + l) * NPTS + p];
            const bool xi0 = (x0 >= 0) & (x0 < Wl);
            const bool xi1 = (x0 + 1 >= 0) & (x0 + 1 < Wl);
            const bool yi0 = (y0 >= 0) & (y0 < Hl);
            const bool yi1 = (y0 + 1 >= 0) & (y0 + 1 < Hl);
            const int rb = st + y0 * Wl + x0;
            float4 sv = make_float4(0.f, 0.f, 0.f, 0.f);
            if (yi0 & xi0) {
                const float w00 = (1.f - wy) * (1.f - wx);
                const float4 t4 = *(const float4*)(vc + ((size_t)rb << 8));
                sv.x += w00 * t4.x; sv.y += w00 * t4.y; sv.z += w00 * t4.z; sv.w += w00 * t4.w;
            }
            if (yi0 & xi1) {
                const float w01 = (1.f - wy) * wx;
                const float4 t4 = *(const float4*)(vc + ((size_t)(rb + 1) << 8));
                sv.x += w01 * t4.x; sv.y += w01 * t4.y; sv.z += w01 * t4.z; sv.w += w01 * t4.w;
            }
            if (yi1 & xi0) {
                const float w10 = wy * (1.f - wx);
                const float4 t4 = *(const float4*)(vc + ((size_t)(rb + Wl) << 8));
                sv.x += w10 * t4.x; sv.y += w10 * t4.y; sv.z += w10 * t4.z; sv.w += w10 * t4.w;
            }
            if (yi1 & xi1) {
                const float w11 = wy * wx;
                const float4 t4 = *(const float4*)(vc + ((size_t)(rb + Wl + 1) << 8));
                sv.x += w11 * t4.x; sv.y += w11 * t4.y; sv.z += w11 * t4.z; sv.w += w11 * t4.w;
            }
            acc.x += a * sv.x; acc.y += a * sv.y; acc.z += a * sv.z; acc.w += a * sv.w;
        }
    }
    if (wave > 0) *(float4*)&red[wave - 1][ch0] = acc;
    __syncthreads();
    if (wave == 0) {
#pragma unroll
        for (int w2 = 0; w2 < 3; w2++) {
            const float4 r4 = *(const float4*)&red[w2][ch0];
            acc.x += r4.x; acc.y += r4.y; acc.z += r4.z; acc.w += r4.w;
        }
        *(float4*)(S + (size_t)n * EDIM + ch0) = acc;
    }
}

// ---------------- temporal align (4x4 inverse fused, computed per block) -------------
__global__ __launch_bounds__(256) void talign_k(const float* __restrict__ prev,
                                                const float* __restrict__ motion,
                                                float* __restrict__ out)
{
    __shared__ float sinv[16];
    if (threadIdx.x == 0) {
        float a[4][8];
        for (int i = 0; i < 4; i++)
            for (int j = 0; j < 4; j++) { a[i][j] = motion[i * 4 + j];
                                          a[i][4 + j] = (i == j) ? 1.f : 0.f; }
        for (int col = 0; col < 4; col++) {
            int piv = col;
            for (int r = col + 1; r < 4; r++)
                if (fabsf(a[r][col]) > fabsf(a[piv][col])) piv = r;
            if (piv != col)
                for (int j = 0; j < 8; j++) { float tp = a[col][j];
                                              a[col][j] = a[piv][j]; a[piv][j] = tp; }
            float idv = 1.f / a[col][col];
            for (int j = 0; j < 8; j++) a[col][j] *= idv;
            for (int r = 0; r < 4; r++) {
                if (r == col) continue;
                float f = a[r][col];
                for (int j = 0; j < 8; j++) a[r][j] -= f * a[col][j];
            }
        }
        for (int i = 0; i < 4; i++)
            for (int j = 0; j < 4; j++) sinv[i * 4 + j] = a[i][4 + j];
    }
    __syncthreads();
    const int pix = blockIdx.x, e = threadIdx.x;
    const int r = pix / 50, c = pix % 50;
    const float rx = (c + 0.5f) * 4.0f - 60.f;
    const float ry = (r + 0.5f) * 2.4f - 60.f;
    const float gx = sinv[0] * rx + sinv[1] * ry + sinv[3];
    const float gy = sinv[4] * rx + sinv[5] * ry + sinv[7];
    const float nx = (gx + 60.f) * 0.01f - 1.f;
    const float ny = (gy + 60.f) * (1.f / 60.f) - 1.f;
    const float x = (nx + 1.f) * 25.f - 0.5f;
    const float y = (ny + 1.f) * 25.f - 0.5f;
    const float xf = floorf(x), yf = floorf(y);
    const float wx = x - xf, wy = y - yf;
    const int x0 = (int)xf, y0 = (int)yf;
    bool xi0 = (x0 >= 0 && x0 < 50), xi1 = (x0 + 1 >= 0 && x0 + 1 < 50);
    bool yi0 = (y0 >= 0 && y0 < 50), yi1 = (y0 + 1 >= 0 && y0 + 1 < 50);
    float s = 0.f;
    if (yi0 && xi0) s += (1.f - wy) * (1.f - wx) * prev[(size_t)(y0 * 50 + x0) * EDIM + e];
    if (yi0 && xi1) s += (1.f - wy) * wx         * prev[(size_t)(y0 * 50 + x0 + 1) * EDIM + e];
    if (yi1 && xi0) s += wy * (1.f - wx)         * prev[(size_t)((y0 + 1) * 50 + x0) * EDIM + e];
    if (yi1 && xi1) s += wy * wx                 * prev[(size_t)((y0 + 1) * 50 + x0 + 1) * EDIM + e];
    out[(size_t)pix * EDIM + e] = s;
}

// ---------------- MHA flash, MFMA, split-KV (bf16 inputs; full-tile fast path) ------
__global__ __launch_bounds__(256) void mha_mfma_k(const unsigned short* __restrict__ Qbf,
                                                  const unsigned short* __restrict__ Kbf,
                                                  const unsigned short* __restrict__ VbfT,
                                                  float* __restrict__ pacc,
                                                  float* __restrict__ pml)
{
    const int h = blockIdx.y;
    const int q0 = blockIdx.x * 64;
    const int chunk = blockIdx.z;
    const int kv0 = chunk * KVCH;
    const int kv1 = min(NPIX, kv0 + KVCH);
    const int tid = threadIdx.x;
    const int wave = tid >> 6, lane = tid & 63;
    const int fr = lane & 15, fk = lane >> 4;

    __shared__ unsigned short Qs[64][44];
    __shared__ unsigned short Ks[64][44];
    __shared__ unsigned short Vt[32][76];
    __shared__ unsigned short Ps[4][16][76];

    const int srow = tid >> 2, scs = tid & 3;
    {
        const int gq = q0 + srow;
        if (gq < NPIX)
            *(short8*)&Qs[srow][scs * 8] =
                *(const short8*)&Qbf[(size_t)gq * EDIM + h * HDIM + scs * 8];
        else {
            short8 z = {0,0,0,0,0,0,0,0};
            *(short8*)&Qs[srow][scs * 8] = z;
        }
    }
    __syncthreads();
    const short8 aq = *(const short8*)&Qs[wave * 16 + fr][fk * 8];

    float m[4], l[4];
    float4v o0, o1;
#pragma unroll
    for (int r = 0; r < 4; r++) { m[r] = -3.0e38f; l[r] = 0.f; o0[r] = 0.f; o1[r] = 0.f; }

    const int vd = tid >> 3, vpart = tid & 7;   // V staging: 32 rows x 8 chunks
    for (int kb = kv0; kb < kv1; kb += 64) {
        __syncthreads();
        {
            const int gk = kb + srow;
            if (gk < kv1)
                *(short8*)&Ks[srow][scs * 8] =
                    *(const short8*)&Kbf[(size_t)gk * EDIM + h * HDIM + scs * 8];
            else {
                short8 z = {0,0,0,0,0,0,0,0};
                *(short8*)&Ks[srow][scs * 8] = z;
            }
            const unsigned short* vrow = VbfT + (size_t)(h * HDIM + vd) * VTROW;
            const int base = kb + vpart * 8;
            if (base + 8 <= kv1) {
                *(short8*)&Vt[vd][vpart * 8] = *(const short8*)&vrow[base];
            } else {
#pragma unroll
                for (int j = 0; j < 8; j++)
                    Vt[vd][vpart * 8 + j] = (base + j < kv1) ? vrow[base + j] : 0;
            }
        }
        __syncthreads();
        float4v s[4];
#pragma unroll
        for (int t = 0; t < 4; t++) {
            const short8 bk = *(const short8*)&Ks[t * 16 + fr][fk * 8];
            float4v z; z[0] = 0.f; z[1] = 0.f; z[2] = 0.f; z[3] = 0.f;
            s[t] = __builtin_amdgcn_mfma_f32_16x16x32_bf16(aq, bk, z, 0, 0, 0);
        }
        if (kb + 64 > kv1) {   // partial tile: mask invalid kv columns
#pragma unroll
            for (int t = 0; t < 4; t++) {
                const int colg = kb + t * 16 + fr;
                if (colg >= kv1) { s[t][0] = -3.0e38f; s[t][1] = -3.0e38f;
                                   s[t][2] = -3.0e38f; s[t][3] = -3.0e38f; }
            }
        }
        float cand[4];
#pragma unroll
        for (int r = 0; r < 4; r++)
            cand[r] = fmaxf(fmaxf(s[0][r], s[1][r]), fmaxf(s[2][r], s[3][r]));
#pragma unroll
        for (int off = 1; off < 16; off <<= 1)
#pragma unroll
            for (int r = 0; r < 4; r++)
                cand[r] = fmaxf(cand[r], __shfl_xor(cand[r], off));
        float corr[4];
#pragma unroll
        for (int r = 0; r < 4; r++) {
            const float mn = fmaxf(m[r], cand[r]);
            corr[r] = __expf(m[r] - mn);
            m[r] = mn;
        }
        float psum[4];
#pragma unroll
        for (int r = 0; r < 4; r++) psum[r] = 0.f;
#pragma unroll
        for (int t = 0; t < 4; t++)
#pragma unroll
            for (int r = 0; r < 4; r++) {
                const float p = __expf(s[t][r] - m[r]);
                psum[r] += p;
                Ps[wave][fk * 4 + r][t * 16 + fr] = f2bf(p);
            }
#pragma unroll
        for (int off = 1; off < 16; off <<= 1)
#pragma unroll
            for (int r = 0; r < 4; r++)
                psum[r] += __shfl_xor(psum[r], off);
#pragma unroll
        for (int r = 0; r < 4; r++) {
            l[r] = l[r] * corr[r] + psum[r];
            o0[r] *= corr[r];
            o1[r] *= corr[r];
        }
        const short8 ap0 = *(const short8*)&Ps[wave][fr][fk * 8];
        const short8 ap1 = *(const short8*)&Ps[wave][fr][32 + fk * 8];
        {
            const short8 bv0 = *(const short8*)&Vt[fr][fk * 8];
            const short8 bv1 = *(const short8*)&Vt[fr][32 + fk * 8];
            o0 = __builtin_amdgcn_mfma_f32_16x16x32_bf16(ap0, bv0, o0, 0, 0, 0);
            o0 = __builtin_amdgcn_mfma_f32_16x16x32_bf16(ap1, bv1, o0, 0, 0, 0);
        }
        {
            const short8 bv0 = *(const short8*)&Vt[16 + fr][fk * 8];
            const short8 bv1 = *(const short8*)&Vt[16 + fr][32 + fk * 8];
            o1 = __builtin_amdgcn_mfma_f32_16x16x32_bf16(ap0, bv0, o1, 0, 0, 0);
            o1 = __builtin_amdgcn_mfma_f32_16x16x32_bf16(ap1, bv1, o1, 0, 0, 0);
        }
    }
#pragma unroll
    for (int r = 0; r < 4; r++) {
        const int q = q0 + wave * 16 + fk * 4 + r;
        if (q < NPIX) {
            const size_t pi = ((size_t)chunk * NPIX + q) * NHEADS + h;
            pacc[pi * 32 + fr]      = o0[r];
            pacc[pi * 32 + 16 + fr] = o1[r];
            if (fr == 0) { pml[pi * 2] = m[r]; pml[pi * 2 + 1] = l[r]; }
        }
    }
}

// ---------------- merge split-KV partials (bf16 output for ta_out GEMM) -------------
__global__ __launch_bounds__(256) void mha_merge_k(const float* __restrict__ pacc,
                                                   const float* __restrict__ pml,
                                                   unsigned short* __restrict__ O)
{
    const int q = blockIdx.x;
    const int tid = threadIdx.x;
    const int h = tid >> 5, d = tid & 31;
    float ms[NCHUNK], ls[NCHUNK];
    float gm = -3.0e38f;
#pragma unroll
    for (int c = 0; c < NCHUNK; c++) {
        const size_t pi = ((size_t)c * NPIX + q) * NHEADS + h;
        ms[c] = pml[pi * 2];
        ls[c] = pml[pi * 2 + 1];
        gm = fmaxf(gm, ms[c]);
    }
    float gl = 0.f, s = 0.f;
#pragma unroll
    for (int c = 0; c < NCHUNK; c++) {
        const size_t pi = ((size_t)c * NPIX + q) * NHEADS + h;
        float w = __expf(ms[c] - gm);
        gl += ls[c] * w;
        s  += pacc[pi * 32 + d] * w;
    }
    O[(size_t)q * EDIM + h * HDIM + d] = f2bf(s / gl);
}

// =====================================================================================
extern "C" void kernel_launch(void* const* d_in, const int* in_sizes, int n_in,
                              void* d_out, int out_size, void* d_ws, size_t ws_size,
                              hipStream_t stream)
{
    const float* bev_emb  = (const float*)d_in[0];
    const float* bev_pose = (const float*)d_in[1];
    const float* ta_in_w  = (const float*)d_in[2];
    const float* ta_in_b  = (const float*)d_in[3];
    const float* ta_out_w = (const float*)d_in[4];
    const float* ta_out_b = (const float*)d_in[5];
    const float* so_w     = (const float*)d_in[6];
    const float* so_b     = (const float*)d_in[7];
    const float* aw_w     = (const float*)d_in[8];
    const float* aw_b     = (const float*)d_in[9];
    const float* vp_w     = (const float*)d_in[10];
    const float* vp_b     = (const float*)d_in[11];
    const float* op_w     = (const float*)d_in[12];
    const float* op_b     = (const float*)d_in[13];
    const float* ffn_w1   = (const float*)d_in[14];
    const float* ffn_b1   = (const float*)d_in[15];
    const float* ffn_w2   = (const float*)d_in[16];
    const float* ffn_b2   = (const float*)d_in[17];
    const float* n1_g     = (const float*)d_in[18];
    const float* n1_b     = (const float*)d_in[19];
    const float* n2_g     = (const float*)d_in[20];
    const float* n2_b     = (const float*)d_in[21];
    const float* n3_g     = (const float*)d_in[22];
    const float* n3_b     = (const float*)d_in[23];
    const float* feat0    = (const float*)d_in[24];
    const float* feat1    = (const float*)d_in[25];
    const float* feat2    = (const float*)d_in[26];
    const float* l2i      = (const float*)d_in[27];
    const float* ego      = (const float*)d_in[28];

    float* w = (float*)d_ws;
    float* ws_inv   = w;                    // 16 (unused; layout kept)
    float* validn   = w + 16;               // 10000
    float* vbm      = w + 10016;            // 2500
    float* bev_cur  = w + 16384;
    float* bev_prev = bev_cur  + 640000;
    float* qin      = bev_prev + 640000;    // featT alias base
    float* kin      = qin      + 640000;    // ffn_h alias
    float* prev_al  = kin      + 640000;
    float* Qb       = prev_al  + 640000;
    float* Kb       = Qb       + 640000;
    float* Vb       = Kb       + 640000;
    float* attn_pre = Vb       + 640000;
    float* attn_o   = attn_pre + 640000;
    float* off_buf  = attn_o   + 640000;    // 2500*288 (so|aw raw)
    float* aw_raw   = off_buf  + 480000;    // (span)
    float* aw_soft  = aw_raw   + 240000;    // 2500*96
    float* Sm       = aw_soft  + 240000;    // 2500*256 (unused now)
    float* vproj    = Sm       + 640000;    // 6*8400*256
    float* Sbuf     = Qb;                   // alias (10000*256)
    float* ffn_h    = kin;                  // alias span (bf16 use)
    float* pacc     = vproj;                // alias: vproj region free during MHA
    float* pml      = vproj + (size_t)NCHUNK * NPIX * NHEADS * 32;
    unsigned short* featT = (unsigned short*)qin;   // bf16 alias, dead after vproj GEMM
    float* uvtab = attn_o;                  // dead between vproj GEMM and op-proj GEMM
    unsigned short* Qbf  = (unsigned short*)attn_o;            // 640000 ushorts
    unsigned short* Kbf  = Qbf + 640000;                       // 640000 ushorts
    unsigned short* VbfT = (unsigned short*)off_buf;           // 256*2504 = 641024
    unsigned short* attn_pre_bf = (unsigned short*)attn_pre;   // bf16 attn_pre
    unsigned short* ffn_hbf = (unsigned short*)ffn_h;          // bf16 ffn hidden
    (void)aw_raw; (void)Qb; (void)Kb; (void)Vb; (void)ws_inv; (void)Sm;

    auto GEMM = [&](const float* A, const float* Wp, const float* bias, float* C,
                    int M, int N, int K, int act) {
        dim3 g((N + 63) / 64, (M + 63) / 64);
        if (act)
            gemm64_k<1, 0><<<g, 256, 0, stream>>>(A, nullptr, Wp, bias, C, M, N, K,
                                                  0, 0, 0, 0);
        else
            gemm64_k<0, 0><<<g, 256, 0, stream>>>(A, nullptr, Wp, bias, C, M, N, K,
                                                  0, 0, 0, 0);
    };

    for (int t = 0; t < 2; t++) {
        // layer input (`bev`) is always bev_emb; only prev carries state across t.
        const float* cur = bev_emb;
        if (t > 0) {
            // temporal align (4x4 inverse fused per block)
            talign_k<<<NPIX, 256, 0, stream>>>(bev_prev, ego + (size_t)t * 16, prev_al);
            // merged QKV projection: one launch, z selects Q/K/V (480 blocks co-run)
            gemm_qkv_k<<<dim3(4, 40, 3), 256, 0, stream>>>(
                bev_emb, prev_al, bev_pose, ta_in_w, ta_in_b, Qbf, Kbf, VbfT);
            mha_mfma_k<<<dim3((NPIX + 63) / 64, NHEADS, NCHUNK), 256, 0, stream>>>(
                Qbf, Kbf, VbfT, pacc, pml);
            mha_merge_k<<<NPIX, 256, 0, stream>>>(pacc, pml, attn_pre_bf);
            // ta_out projection from bf16 attention output
            gemm64b_k<<<dim3(4, 40), 256, 0, stream>>>(
                attn_pre_bf, ta_out_w, ta_out_b, attn_o, NPIX, EDIM, EDIM, 0, 0);
            resid_ln_k<0><<<NPIX, 256, 0, stream>>>(bev_emb, attn_o, nullptr, nullptr,
                                                    n1_g, n1_b, bev_cur);
            cur = bev_cur;
        }
        // ---- spatial cross-attention: merged feat transpose, then vproj+soaw merged -
        transpose_feat_all_k<<<dim3(263, 8, 6), 256, 0, stream>>>(
            feat0, feat1, feat2, t, featT);
        gemm_vs_k<<<dim3(5, 132, 7), 256, 0, stream>>>(
            featT, vp_w, vp_b, vproj, cur, bev_pose, so_w, aw_w, so_b, aw_b, off_buf);
        // fused uv precompute + vbm + aw softmax (one launch)
        uv_aw_k<<<119, 256, 0, stream>>>(l2i, t, off_buf, uvtab, validn, aw_soft, vbm);
        spatial_sample_k<<<NQTOT, 256, 0, stream>>>(vproj, off_buf, aw_soft, uvtab, Sbuf);
        // op projection with fused Z-reduce A-staging (bias folded into LN via vbm)
        gemm_op_k<<<dim3(4, 40), 256, 0, stream>>>(Sbuf, validn, op_w, attn_o);
        resid_ln_k<0><<<NPIX, 256, 0, stream>>>(cur, attn_o, op_b, vbm,
                                                n2_g, n2_b, bev_cur);
        // FFN: w1 -> bf16 hidden (ReLU fused), w2 from bf16
        gemm64o_k<1, 0><<<dim3(8, 40), 256, 0, stream>>>(
            bev_cur, nullptr, ffn_w1, ffn_b1, ffn_hbf, NPIX, FFND, EDIM);
        gemm64b_k<<<dim3(4, 40), 256, 0, stream>>>(
            ffn_hbf, ffn_w2, ffn_b2, attn_o, NPIX, EDIM, FFND, 0, 0);
        // t=0: LN -> bev_prev; t=1: LN writes TRANSPOSED final output directly
        if (t == 0)
            resid_ln_k<0><<<NPIX, 256, 0, stream>>>(bev_cur, attn_o, nullptr, nullptr,
                                                    n3_g, n3_b, bev_prev);
        else
            resid_ln_k<1><<<NPIX, 256, 0, stream>>>(bev_cur, attn_o, nullptr, nullptr,
                                                    n3_g, n3_b, (float*)d_out);
    }
}